// Round 13
// baseline (319.088 us; speedup 1.0000x reference)
//
#include <hip/hip_runtime.h>

typedef unsigned short u16;
typedef unsigned int   u32;
typedef short bf16x8 __attribute__((ext_vector_type(8)));
typedef float f32x4  __attribute__((ext_vector_type(4)));
typedef unsigned int u32x4 __attribute__((ext_vector_type(4)));

#define NTOK   2048
#define DMODEL 1024
#define NH     16
#define HD     64

__device__ __forceinline__ u16 f2bf(float f){
  u32 x = __float_as_uint(f);
  return (u16)((x + 0x7fffu + ((x>>16)&1u)) >> 16);   // RNE
}
__device__ __forceinline__ void unpack8(uint4 u, float* f){
  f[0]=__uint_as_float(u.x<<16); f[1]=__uint_as_float(u.x&0xffff0000u);
  f[2]=__uint_as_float(u.y<<16); f[3]=__uint_as_float(u.y&0xffff0000u);
  f[4]=__uint_as_float(u.z<<16); f[5]=__uint_as_float(u.z&0xffff0000u);
  f[6]=__uint_as_float(u.w<<16); f[7]=__uint_as_float(u.w&0xffff0000u);
}
// pack 2 f32 -> 2 bf16 (RNE) in one VALU inst. lo = bf16(a), hi = bf16(b).
__device__ __forceinline__ u32 pk_bf16(float a, float b){
  u32 r;
  asm("v_cvt_pk_bf16_f32 %0, %1, %2" : "=v"(r) : "v"(a), "v"(b));
  return r;
}

// async global->LDS, 16B per lane. LDS dest must be wave-uniform base + lane*16 (linear).
#define GLOAD_LDS16(GP, LP) \
  __builtin_amdgcn_global_load_lds((__attribute__((address_space(1))) const void*)(GP), \
                                   (__attribute__((address_space(3))) void*)(LP), 16, 0, 0)

// =====================================================================================
// FAST PATH
// =====================================================================================

// W [K][N] fp32 -> Wt [N][K] bf16 (transpose + cvt). grid (N/64, K/64), block 256.
__global__ __launch_bounds__(256) void k_tcvt(const float* __restrict__ W, u16* __restrict__ Wt,
                                              int K, int N)
{
  const int tid = threadIdx.x;
  const int n0 = blockIdx.x * 64, k0 = blockIdx.y * 64;
  __shared__ float tileF[64*68];
  {
    int kk = tid >> 2, nseg = (tid & 3) * 16;
    const float* src = W + (size_t)(k0 + kk)*N + n0 + nseg;
    #pragma unroll
    for (int i=0;i<4;i++)
      *(float4*)&tileF[kk*68 + nseg + i*4] = *(const float4*)(src + i*4);
  }
  __syncthreads();
  {
    int n = tid >> 2, kseg = (tid & 3) * 16;
    u16 tmp[16];
    #pragma unroll
    for (int j=0;j<16;j++) tmp[j] = f2bf(tileF[(kseg + j)*68 + n]);
    uint4 o0, o1;
    o0.x=(u32)tmp[0]|((u32)tmp[1]<<16);  o0.y=(u32)tmp[2]|((u32)tmp[3]<<16);
    o0.z=(u32)tmp[4]|((u32)tmp[5]<<16);  o0.w=(u32)tmp[6]|((u32)tmp[7]<<16);
    o1.x=(u32)tmp[8]|((u32)tmp[9]<<16);  o1.y=(u32)tmp[10]|((u32)tmp[11]<<16);
    o1.z=(u32)tmp[12]|((u32)tmp[13]<<16);o1.w=(u32)tmp[14]|((u32)tmp[15]<<16);
    u16* dst = Wt + (size_t)(n0 + n)*K + k0 + kseg;
    *(uint4*)dst       = o0;
    *(uint4*)(dst + 8) = o1;
  }
}

// Generic bf16 MFMA GEMM: out[M][N] = A[M][K] @ Bt[N][K]^T + bias.
// M-tile 64, N-tile 128. global_load_lds width-16 staging, linear LDS tiles.
// qkvmode=1: out bf16, cols<1024 scaled by 1/8.  qkvmode=0: out fp32 = acc+bias+resid.
// grid (N/128, M/64), block 256 (4 waves, 2x2; wave owns 32 rows x 64 cols).
__global__ __launch_bounds__(256) void k_gemm(
    const u16* __restrict__ A, const u16* __restrict__ Bt,
    const float* __restrict__ bias, const float* __restrict__ resid,
    u16* __restrict__ outb, float* __restrict__ outf,
    int M, int N, int K, int qkvmode)
{
  const int tid  = threadIdx.x;
  const int lane = tid & 63, wv = tid >> 6;
  const int quad = lane >> 4, low = lane & 15;
  const int wm = wv >> 1, wn = wv & 1;
  const int m0 = blockIdx.y * 64, n0 = blockIdx.x * 128;

  __shared__ u16 Al[64*64];
  __shared__ u16 Bl[128*64];

  const f32x4 zz = {0.f,0.f,0.f,0.f};
  f32x4 acc[2][4];
  #pragma unroll
  for (int mt=0;mt<2;mt++)
    #pragma unroll
    for (int nt=0;nt<4;nt++) acc[mt][nt] = zz;

  for (int k0 = 0; k0 < K; k0 += 64){
    #pragma unroll
    for (int s = 0; s < 2; s++){
      int slot = tid + s*256;
      int row = slot >> 3, seg = (slot & 7) * 8;
      GLOAD_LDS16(A + (size_t)(m0+row)*K + k0 + seg, &Al[slot*8]);
    }
    #pragma unroll
    for (int s = 0; s < 4; s++){
      int slot = tid + s*256;
      int row = slot >> 3, seg = (slot & 7) * 8;
      GLOAD_LDS16(Bt + (size_t)(n0+row)*K + k0 + seg, &Bl[slot*8]);
    }
    __syncthreads();
    #pragma unroll
    for (int ks = 0; ks < 64; ks += 32){
      bf16x8 af[2], bfr[4];
      #pragma unroll
      for (int mt=0; mt<2; mt++)
        af[mt] = *(const bf16x8*)&Al[(wm*32 + mt*16 + low)*64 + ks + quad*8];
      #pragma unroll
      for (int nt=0; nt<4; nt++)
        bfr[nt] = *(const bf16x8*)&Bl[(wn*64 + nt*16 + low)*64 + ks + quad*8];
      #pragma unroll
      for (int mt=0; mt<2; mt++)
        #pragma unroll
        for (int nt=0; nt<4; nt++)
          // swapped operands: D row(quad*4+rg)=n, col(low)=m -> vectorized n-stores
          acc[mt][nt] = __builtin_amdgcn_mfma_f32_16x16x32_bf16(bfr[nt], af[mt], acc[mt][nt], 0,0,0);
    }
    __syncthreads();
  }

  #pragma unroll
  for (int mt=0; mt<2; mt++){
    int m = m0 + wm*32 + mt*16 + low;
    #pragma unroll
    for (int nt=0; nt<4; nt++){
      int n = n0 + wn*64 + nt*16 + quad*4;
      float4 bb = *(const float4*)(bias + n);
      float v0 = acc[mt][nt][0] + bb.x;
      float v1 = acc[mt][nt][1] + bb.y;
      float v2 = acc[mt][nt][2] + bb.z;
      float v3 = acc[mt][nt][3] + bb.w;
      if (qkvmode){
        float sc = (n < 1024) ? 0.125f : 1.0f;
        v0*=sc; v1*=sc; v2*=sc; v3*=sc;
        uint2 pk;
        pk.x = (u32)f2bf(v0) | ((u32)f2bf(v1)<<16);
        pk.y = (u32)f2bf(v2) | ((u32)f2bf(v3)<<16);
        *(uint2*)(outb + (size_t)m*N + n) = pk;
      } else {
        float4 xr = *(const float4*)(resid + (size_t)m*N + n);
        float4 o = {v0+xr.x, v1+xr.y, v2+xr.z, v3+xr.w};
        *(float4*)(outf + (size_t)m*N + n) = o;
      }
    }
  }
}

// transpose v: vt[h][d][m] bf16. grid (32 mtiles, 16 h), block 256.
__global__ __launch_bounds__(256) void k_vt(const u16* __restrict__ qkvb, u16* __restrict__ vt)
{
  const int m0 = blockIdx.x * 64;
  const int h  = blockIdx.y;
  const int tid = threadIdx.x;
  __shared__ u16 tile[64][72];
  {
    int row = tid >> 2, seg = (tid & 3) * 8;
    const u16* src = qkvb + (size_t)(m0 + row)*3072 + 2048 + h*64;
    *(uint4*)&tile[row][seg]      = *(const uint4*)(src + seg);
    *(uint4*)&tile[row][32 + seg] = *(const uint4*)(src + 32 + seg);
  }
  __syncthreads();
  {
    int d = tid >> 2, mseg = (tid & 3) * 16;
    __align__(16) u16 tmp[16];
    #pragma unroll
    for (int j=0;j<16;j++) tmp[j] = tile[mseg + j][d];
    u16* dst = vt + (size_t)(h*64 + d)*2048 + m0 + mseg;
    *(uint4*)dst       = *(uint4*)&tmp[0];
    *(uint4*)(dst + 8) = *(uint4*)&tmp[8];
  }
}

// QK + softmax-numerator kernel. grid (64 ntiles of 32 rows, 16 heads), block 512
// (8 waves; each wave owns a 256-key segment = 8 steps of 32 keys).
// Key-permuted loads (key = ks + (low>>2)*8 + kt*4 + (low&3)) so a lane's 8 p's
// across both kt are 8 CONTIGUOUS keys -> one 16B store per row per step.
// pbuf stores are NONTEMPORAL via clang ext-vector u32x4 (streaming; keep L2 for
// K/pk; probe whether 172-vs-134MB write amplification is partial-line eviction).
// bf16 packing via v_cvt_pk_bf16_f32. Constant-shift softmax: p = exp(l-48).
__global__ __launch_bounds__(512, 4) void k_attn_qk(
    const u16* __restrict__ qkvb,
    const float* __restrict__ pqb, const float* __restrict__ pkb,
    u16* __restrict__ pbuf, float* __restrict__ invSbuf)
{
  const int tid  = threadIdx.x;
  const int lane = tid & 63, wv = tid >> 6;
  const int quad = lane >> 4, low = lane & 15;
  const int n0 = blockIdx.x * 32;
  const int h  = blockIdx.y;

  __shared__ float rs[8][32];

  bf16x8 qf[2][2];
  #pragma unroll
  for (int rt=0; rt<2; rt++)
    #pragma unroll
    for (int df=0; df<2; df++)
      qf[rt][df] = *(const bf16x8*)(qkvb + (size_t)(n0 + rt*16 + low)*3072 + h*64 + df*32 + quad*8);

  // pq for this lane's own q-rows (rt*16+low)
  float4 pqr[2];
  #pragma unroll
  for (int rt=0; rt<2; rt++)
    pqr[rt] = *(const float4*)(pqb + (size_t)(n0 + rt*16 + low)*64 + h*4);

  const f32x4 zz = {0.f,0.f,0.f,0.f};
  float psum[2] = {0.f, 0.f};

  const int kperm = ((low>>2)<<3) + (low&3);   // + kt*4 per kt

  for (int step=0; step<8; step++){
    const int ks = (wv<<8) + (step<<5);
    u32x4 st0, st1;
    #pragma unroll
    for (int kt=0; kt<2; kt++){
      const u16* kbase = qkvb + (size_t)(ks + kperm + kt*4)*3072 + 1024 + h*64 + quad*8;
      bf16x8 kf0 = *(const bf16x8*)(kbase);
      bf16x8 kf1 = *(const bf16x8*)(kbase + 32);
      // swapped: D-row = key-slot (quad*4+rg) -> key ks + quad*8 + kt*4 + rg
      f32x4 a0 = zz, a1 = zz;
      a0 = __builtin_amdgcn_mfma_f32_16x16x32_bf16(kf0, qf[0][0], a0, 0,0,0);
      a0 = __builtin_amdgcn_mfma_f32_16x16x32_bf16(kf1, qf[0][1], a0, 0,0,0);
      a1 = __builtin_amdgcn_mfma_f32_16x16x32_bf16(kf0, qf[1][0], a1, 0,0,0);
      a1 = __builtin_amdgcn_mfma_f32_16x16x32_bf16(kf1, qf[1][1], a1, 0,0,0);
      float pv0[4], pv1[4];
      float s0 = 0.f, s1 = 0.f;
      #pragma unroll
      for (int rg=0; rg<4; rg++){
        float4 pk = *(const float4*)(pkb + (size_t)(ks + quad*8 + kt*4 + rg)*64 + h*4);
        float pkc = pk.w - 48.f;
        float4 pq0 = pqr[0], pq1 = pqr[1];
        float b0 = pq0.w + pkc - 2.f*(pq0.x*pk.x + pq0.y*pk.y + pq0.z*pk.z);
        float b1 = pq1.w + pkc - 2.f*(pq1.x*pk.x + pq1.y*pk.y + pq1.z*pk.z);
        pv0[rg] = __expf(a0[rg] + b0);
        pv1[rg] = __expf(a1[rg] + b1);
        s0 += pv0[rg]; s1 += pv1[rg];
      }
      psum[0] += s0; psum[1] += s1;
      u32 wa = pk_bf16(pv0[0], pv0[1]);
      u32 wb = pk_bf16(pv0[2], pv0[3]);
      u32 wc = pk_bf16(pv1[0], pv1[1]);
      u32 wd = pk_bf16(pv1[2], pv1[3]);
      if (kt == 0){ st0.x = wa; st0.y = wb; st1.x = wc; st1.y = wd; }
      else        { st0.z = wa; st0.w = wb; st1.z = wc; st1.w = wd; }
    }
    // row (n0+low) keys [ks+quad*8, ks+quad*8+8) -- 16B nt-store, 4 quads cover 64B
    __builtin_nontemporal_store(st0,
        (u32x4*)(pbuf + ((size_t)h*NTOK + n0 + low)*NTOK      + ks + quad*8));
    __builtin_nontemporal_store(st1,
        (u32x4*)(pbuf + ((size_t)h*NTOK + n0 + 16 + low)*NTOK + ks + quad*8));
  }

  // psum: lane-local over its keys; reduce across quads (lane bits 4,5)
  #pragma unroll
  for (int rt=0; rt<2; rt++){
    psum[rt] += __shfl_xor(psum[rt], 16);
    psum[rt] += __shfl_xor(psum[rt], 32);
  }
  if (quad == 0){
    rs[wv][low]      = psum[0];
    rs[wv][16 + low] = psum[1];
  }
  __syncthreads();
  if (tid < 32){
    float s = rs[0][tid] + rs[1][tid] + rs[2][tid] + rs[3][tid]
            + rs[4][tid] + rs[5][tid] + rs[6][tid] + rs[7][tid];
    invSbuf[(size_t)h*NTOK + n0 + tid] = 1.0f / s;
  }
}

// PV as a per-head GEMM: attb[m][h*64+n] = invS[h][m] * sum_k p[h][m][k] * vt[h][n][k].
// M-tile 64, BK=128, 1-D grid 512 (XCD-pinned: head h on XCD h&7), block 256 (4 waves).
// P DIRECT-TO-REGISTER (T14 issue-early): P has zero reuse -> LDS staging was pure
// overhead coupling the P stream to the barrier. pA/pB named register double-buffer,
// tile t+1's loads issued before computing tile t. Only V (shared by 4 waves) stays
// in LDS (2x16KB dbuf, XOR-swizzled both-sides per rule #21).
__global__ __launch_bounds__(256) void k_pv(
    const u16* __restrict__ pbuf, const u16* __restrict__ vt,
    const float* __restrict__ invSbuf, u16* __restrict__ attb)
{
  const int tid  = threadIdx.x;
  const int lane = tid & 63, wv = tid >> 6;
  const int quad = lane >> 4, low = lane & 15;
  // bid -> (head, m-tile): xcd = bid&7 hosts heads {xcd, xcd+8}; bijective.
  const int bid  = blockIdx.x;
  const int xcd  = bid & 7;
  const int slot = bid >> 3;                 // 0..63
  const int h    = xcd + ((slot >> 5) << 3); // slot<32 -> xcd, else xcd+8
  const int m0   = (slot & 31) * 64;

  __shared__ u16 Vl[2][64*128];

  const f32x4 zz = {0.f,0.f,0.f,0.f};
  f32x4 acc[4];
  #pragma unroll
  for (int nt=0;nt<4;nt++) acc[nt] = zz;

  const u16* vbase = vt + (size_t)h*64*NTOK;
  // this lane's P row pointer (16B chunk at quad*8 within each 32-col group)
  const u16* prow  = pbuf + (size_t)h*NTOK*NTOK
                   + (size_t)(m0 + wv*16 + low)*NTOK + quad*8;

  const int rsw = (low & 7) << 3;   // read-side XOR for V

  // V staging coordinates (constant across iters)
  const int srow = tid >> 4;              // rows 0..15 (+16 per s)
  const int sseg = (tid & 15) * 8;
  const int ssw  = sseg ^ ((srow & 7) << 3);

#define PV_STAGE_V(VD, K0)                                                           \
  { _Pragma("unroll")                                                                \
    for (int s = 0; s < 4; s++){                                                     \
      int slot_ = tid + s*256;                                                       \
      int row_  = srow + s*16;                                                       \
      GLOAD_LDS16(vbase + (size_t)row_*NTOK + (K0) + ssw, (VD) + slot_*8);           \
    } }

#define PV_LOADP(P0,P1,P2,P3, T)                                                     \
  { const u16* p_ = prow + (size_t)(T)*128;                                          \
    P0 = *(const bf16x8*)(p_);                                                       \
    P1 = *(const bf16x8*)(p_ + 32);                                                  \
    P2 = *(const bf16x8*)(p_ + 64);                                                  \
    P3 = *(const bf16x8*)(p_ + 96); }

#define PV_ONE(VC, KS, PP)                                                           \
  { int col_ = ((KS) + quad*8) ^ rsw;                                                \
    bf16x8 b0_ = *(const bf16x8*)&(VC)[( 0 + low)*128 + col_];                       \
    bf16x8 b1_ = *(const bf16x8*)&(VC)[(16 + low)*128 + col_];                       \
    bf16x8 b2_ = *(const bf16x8*)&(VC)[(32 + low)*128 + col_];                       \
    bf16x8 b3_ = *(const bf16x8*)&(VC)[(48 + low)*128 + col_];                       \
    acc[0] = __builtin_amdgcn_mfma_f32_16x16x32_bf16(b0_, PP, acc[0], 0,0,0);        \
    acc[1] = __builtin_amdgcn_mfma_f32_16x16x32_bf16(b1_, PP, acc[1], 0,0,0);        \
    acc[2] = __builtin_amdgcn_mfma_f32_16x16x32_bf16(b2_, PP, acc[2], 0,0,0);        \
    acc[3] = __builtin_amdgcn_mfma_f32_16x16x32_bf16(b3_, PP, acc[3], 0,0,0); }

#define PV_COMPUTE(VC, P0,P1,P2,P3)                                                  \
  PV_ONE(VC,  0, P0) PV_ONE(VC, 32, P1) PV_ONE(VC, 64, P2) PV_ONE(VC, 96, P3)

  bf16x8 pA0,pA1,pA2,pA3, pB0,pB1,pB2,pB3;
  PV_LOADP(pA0,pA1,pA2,pA3, 0)
  PV_STAGE_V(Vl[0], 0)
  __syncthreads();

  for (int t = 0; t < 16; t += 2){
    // phase A: compute tile t from Vl[0]+pA; prefetch t+1
    PV_STAGE_V(Vl[1], (t+1)*128)
    PV_LOADP(pB0,pB1,pB2,pB3, t+1)
    PV_COMPUTE(Vl[0], pA0,pA1,pA2,pA3)
    __syncthreads();
    // phase B: compute tile t+1 from Vl[1]+pB; prefetch t+2
    if (t + 2 < 16){
      PV_STAGE_V(Vl[0], (t+2)*128)
      PV_LOADP(pA0,pA1,pA2,pA3, t+2)
    }
    PV_COMPUTE(Vl[1], pB0,pB1,pB2,pB3)
    __syncthreads();
  }
#undef PV_STAGE_V
#undef PV_LOADP
#undef PV_ONE
#undef PV_COMPUTE

  {
    int m = m0 + wv*16 + low;
    float inv = invSbuf[(size_t)h*NTOK + m];
    #pragma unroll
    for (int nt=0; nt<4; nt++){
      int n = nt*16 + quad*4;
      u16 t0 = f2bf(acc[nt][0]*inv);
      u16 t1 = f2bf(acc[nt][1]*inv);
      u16 t2 = f2bf(acc[nt][2]*inv);
      u16 t3 = f2bf(acc[nt][3]*inv);
      uint2 o; o.x = (u32)t0 | ((u32)t1<<16); o.y = (u32)t2 | ((u32)t3<<16);
      *(uint2*)(attb + (size_t)m*DMODEL + h*64 + n) = o;
    }
  }
}

// mean_w = (1/16) sum_h p[h][n][m] * invS[h][n]. grid 2048, block 256.
__global__ __launch_bounds__(256) void k_meanw(const u16* __restrict__ pbuf,
    const float* __restrict__ invSbuf, float* __restrict__ out1)
{
  const int n = blockIdx.x, tid = threadIdx.x;
  const int m0 = tid * 8;
  float acc[8];
  #pragma unroll
  for (int i=0;i<8;i++) acc[i]=0.f;
  for (int h=0; h<NH; h++){
    float inv = invSbuf[(size_t)h*NTOK + n] * 0.0625f;
    uint4 u = *(const uint4*)(pbuf + ((size_t)h*NTOK + n)*NTOK + m0);
    float pf[8]; unpack8(u, pf);
    #pragma unroll
    for (int i=0;i<8;i++) acc[i] += pf[i]*inv;
  }
  float4 a = {acc[0],acc[1],acc[2],acc[3]};
  float4 b = {acc[4],acc[5],acc[6],acc[7]};
  float* dst = out1 + (size_t)n*NTOK + m0;
  *(float4*)dst     = a;
  *(float4*)(dst+4) = b;
}

// =====================================================================================
// SHARED kernels
// =====================================================================================

// point projections + (fast path) fused x->bf16 conversion (xb != nullptr).
__global__ __launch_bounds__(128) void k_points(const float* __restrict__ x,
    const float* __restrict__ Wpq, const float* __restrict__ bpq,
    const float* __restrict__ Wpk, const float* __restrict__ bpk,
    float* __restrict__ pqb, float* __restrict__ pkb, u16* __restrict__ xb)
{
  const int n = blockIdx.x, tid = threadIdx.x;
  __shared__ float xr[1024];
  __shared__ float dots[96];
  float4 a = *(const float4*)(x + (size_t)n*DMODEL + tid*4);
  float4 b = *(const float4*)(x + (size_t)n*DMODEL + 512 + tid*4);
  *(float4*)&xr[tid*4]       = a;
  *(float4*)&xr[512 + tid*4] = b;
  if (xb){
    uint2 o1, o2;
    o1.x = (u32)f2bf(a.x) | ((u32)f2bf(a.y)<<16);
    o1.y = (u32)f2bf(a.z) | ((u32)f2bf(a.w)<<16);
    o2.x = (u32)f2bf(b.x) | ((u32)f2bf(b.y)<<16);
    o2.y = (u32)f2bf(b.z) | ((u32)f2bf(b.w)<<16);
    *(uint2*)(xb + (size_t)n*DMODEL + tid*4)       = o1;
    *(uint2*)(xb + (size_t)n*DMODEL + 512 + tid*4) = o2;
  }
  __syncthreads();
  if (tid < 96){
    const float* W  = (tid<48) ? Wpq : Wpk;
    const float* bb = (tid<48) ? bpq : bpk;
    int c = (tid<48) ? tid : tid-48;
    float acc = 0.f;
    for (int k=0;k<DMODEL;k++) acc += xr[k]*W[(size_t)k*48 + c];
    dots[tid] = acc + bb[c];
  }
  __syncthreads();
  if (tid < 96){
    int c = (tid<48)?tid:tid-48;
    int h = c/3, cc = c - h*3;
    float* o = (tid<48)?pqb:pkb;
    o[(size_t)n*64 + h*4 + cc] = dots[tid];
  }
  if (tid < 32){
    int h = tid & 15, isk = tid >> 4;
    int b0 = isk*48 + h*3;
    float a2=dots[b0], b2=dots[b0+1], c2=dots[b0+2];
    ((isk)?pkb:pqb)[(size_t)n*64 + h*4 + 3] = a2*a2+b2*b2+c2*c2;
  }
}

__global__ __launch_bounds__(256) void k_ln(float* __restrict__ res, const float* __restrict__ gamma,
    const float* __restrict__ beta, float* __restrict__ out)
{
  const int n = blockIdx.x, tid = threadIdx.x;
  const int lane = tid & 63, w = tid >> 6;
  __shared__ float red[2][4];
  float4 v = *(const float4*)(res + (size_t)n*DMODEL + tid*4);
  float s  = v.x+v.y+v.z+v.w;
  float s2 = v.x*v.x+v.y*v.y+v.z*v.z+v.w*v.w;
  #pragma unroll
  for (int off=32; off>0; off>>=1){ s += __shfl_xor(s, off); s2 += __shfl_xor(s2, off); }
  if (lane==0){ red[0][w]=s; red[1][w]=s2; }
  __syncthreads();
  float mean = (red[0][0]+red[0][1]+red[0][2]+red[0][3]) * (1.f/1024.f);
  float m2   = (red[1][0]+red[1][1]+red[1][2]+red[1][3]) * (1.f/1024.f);
  float rs = rsqrtf(m2 - mean*mean + 1e-5f);
  float4 g = *(const float4*)(gamma + tid*4);
  float4 b = *(const float4*)(beta  + tid*4);
  float4 o;
  o.x = (v.x-mean)*rs*g.x + b.x;
  o.y = (v.y-mean)*rs*g.y + b.y;
  o.z = (v.z-mean)*rs*g.z + b.z;
  o.w = (v.w-mean)*rs*g.w + b.w;
  *(float4*)(out + (size_t)n*DMODEL + tid*4) = o;
}

// =====================================================================================
// FALLBACK PATH (fp32, small workspace)
// =====================================================================================

__global__ __launch_bounds__(256) void k_qkv_f32(const float* __restrict__ x, const float* __restrict__ W,
        const float* __restrict__ bias, float* __restrict__ qkv)
{
  const int tid = threadIdx.x;
  const int n0  = blockIdx.x * 8;
  const int c0  = blockIdx.y * 1024 + tid * 4;
  __shared__ float xs[8][1024];
  for (int i = tid; i < 2048; i += 256){
    int r = i >> 8, cc = (i & 255) << 2;
    *(float4*)&xs[r][cc] = *(const float4*)(x + (size_t)(n0 + r)*DMODEL + cc);
  }
  __syncthreads();
  float acc[8][4];
  #pragma unroll
  for (int r=0;r<8;r++){ acc[r][0]=0.f;acc[r][1]=0.f;acc[r][2]=0.f;acc[r][3]=0.f; }
  for (int k=0;k<DMODEL;k+=4){
    float4 xr[8];
    #pragma unroll
    for (int r=0;r<8;r++) xr[r] = *(const float4*)&xs[r][k];
    #pragma unroll
    for (int kk=0;kk<4;kk++){
      float4 wf = *(const float4*)(W + (size_t)(k+kk)*3072 + c0);
      #pragma unroll
      for (int r=0;r<8;r++){
        float xv = ((const float*)&xr[r])[kk];
        acc[r][0] += xv*wf.x; acc[r][1] += xv*wf.y;
        acc[r][2] += xv*wf.z; acc[r][3] += xv*wf.w;
      }
    }
  }
  float4 bb = *(const float4*)(bias + c0);
  const float sc = (blockIdx.y == 0) ? 0.125f : 1.0f;
  #pragma unroll
  for (int r=0;r<8;r++){
    float4 o;
    o.x = (acc[r][0]+bb.x)*sc; o.y = (acc[r][1]+bb.y)*sc;
    o.z = (acc[r][2]+bb.z)*sc; o.w = (acc[r][3]+bb.w)*sc;
    *(float4*)(qkv + (size_t)(n0+r)*3072 + c0) = o;
  }
}

__global__ __launch_bounds__(512) void k_out_f32(const float* __restrict__ att, const float* __restrict__ Wo,
    const float* __restrict__ bo, const float* __restrict__ x, float* __restrict__ res)
{
  const int tid = threadIdx.x;
  const int n0 = blockIdx.x * 8;
  const int c0 = tid * 2;
  __shared__ float sA[8][1024];
  for (int i = tid; i < 2048; i += 512){
    int r = i >> 8, cc = (i & 255) << 2;
    *(float4*)&sA[r][cc] = *(const float4*)(att + (size_t)(n0+r)*DMODEL + cc);
  }
  __syncthreads();
  float acc[8][2];
  #pragma unroll
  for (int r=0;r<8;r++){ acc[r][0]=0.f; acc[r][1]=0.f; }
  for (int k=0;k<DMODEL;k+=4){
    float4 ar[8];
    #pragma unroll
    for (int r=0;r<8;r++) ar[r] = *(const float4*)&sA[r][k];
    #pragma unroll
    for (int kk=0;kk<4;kk++){
      float2 wf = *(const float2*)(Wo + (size_t)(k+kk)*DMODEL + c0);
      #pragma unroll
      for (int r=0;r<8;r++){
        float av = ((const float*)&ar[r])[kk];
        acc[r][0] += av*wf.x; acc[r][1] += av*wf.y;
      }
    }
  }
  float2 bb = *(const float2*)(bo + c0);
  #pragma unroll
  for (int r=0;r<8;r++){
    float2 xf = *(const float2*)(x + (size_t)(n0+r)*DMODEL + c0);
    float2 o; o.x = acc[r][0]+bb.x+xf.x; o.y = acc[r][1]+bb.y+xf.y;
    *(float2*)(res + (size_t)(n0+r)*DMODEL + c0) = o;
  }
}

#define NT 4
__global__ __launch_bounds__(256) void k_attn_f32(const float* __restrict__ qkv,
    const float* __restrict__ pqb, const float* __restrict__ pkb,
    float* __restrict__ att, float* __restrict__ meanw)
{
  const int tid = threadIdx.x;
  const int lane = tid & 63, wvid = tid >> 6;
  const int n0 = blockIdx.x * NT;
  __shared__ __align__(16) float wrow[NT][NTOK];
  __shared__ float attp[4][NT][HD];
  __shared__ float redbuf[2][NT][4];
  float wsumr[NT][8];
  #pragma unroll
  for (int r=0;r<NT;r++){
    #pragma unroll
    for (int j=0;j<8;j++) wsumr[r][j]=0.f;
  }
  for (int h=0; h<NH; h++){
    __syncthreads();
    float lg[NT][8];
    {
      float pq0[NT],pq1[NT],pq2[NT],pq3[NT];
      #pragma unroll
      for (int r=0;r<NT;r++){
        const float* pq = pqb + (size_t)(n0+r)*64 + (h<<2);
        pq0[r]=pq[0]; pq1[r]=pq[1]; pq2[r]=pq[2]; pq3[r]=pq[3];
      }
      #pragma unroll
      for (int j=0;j<8;j++){
        int m = tid + (j<<8);
        float4 p = *(const float4*)(pkb + (size_t)m*64 + (h<<2));
        #pragma unroll
        for (int r=0;r<NT;r++)
          lg[r][j] = pq3[r] + p.w - 2.f*(pq0[r]*p.x + pq1[r]*p.y + pq2[r]*p.z);
      }
    }
    for (int c8=0;c8<8;c8++){
      float qv[NT][8];
      #pragma unroll
      for (int r=0;r<NT;r++){
        const float4* qp = (const float4*)(qkv + (size_t)(n0+r)*3072 + (h<<6) + (c8<<3));
        float4 a = qp[0], b = qp[1];
        qv[r][0]=a.x;qv[r][1]=a.y;qv[r][2]=a.z;qv[r][3]=a.w;
        qv[r][4]=b.x;qv[r][5]=b.y;qv[r][6]=b.z;qv[r][7]=b.w;
      }
      #pragma unroll
      for (int j=0;j<8;j++){
        int m = tid + (j<<8);
        const float* kp = qkv + (size_t)m*3072 + 1024 + (h<<6) + (c8<<3);
        float4 k0 = *(const float4*)kp, k1 = *(const float4*)(kp+4);
        #pragma unroll
        for (int r=0;r<NT;r++){
          lg[r][j] += qv[r][0]*k0.x+qv[r][1]*k0.y+qv[r][2]*k0.z+qv[r][3]*k0.w
                    + qv[r][4]*k1.x+qv[r][5]*k1.y+qv[r][6]*k1.z+qv[r][7]*k1.w;
        }
      }
    }
    float mx[NT];
    #pragma unroll
    for (int r=0;r<NT;r++){
      float m0 = lg[r][0];
      #pragma unroll
      for (int j=1;j<8;j++) m0 = fmaxf(m0, lg[r][j]);
      mx[r]=m0;
    }
    #pragma unroll
    for (int off=32; off>0; off>>=1){
      #pragma unroll
      for (int r=0;r<NT;r++) mx[r] = fmaxf(mx[r], __shfl_xor(mx[r], off));
    }
    if (lane==0){
      #pragma unroll
      for (int r=0;r<NT;r++) redbuf[0][r][wvid] = mx[r];
    }
    __syncthreads();
    float ps[NT];
    #pragma unroll
    for (int r=0;r<NT;r++){
      float bm = fmaxf(fmaxf(redbuf[0][r][0],redbuf[0][r][1]),
                       fmaxf(redbuf[0][r][2],redbuf[0][r][3]));
      float s = 0.f;
      #pragma unroll
      for (int j=0;j<8;j++){ float p = __expf(lg[r][j]-bm); lg[r][j]=p; s+=p; }
      ps[r]=s;
    }
    #pragma unroll
    for (int off=32; off>0; off>>=1){
      #pragma unroll
      for (int r=0;r<NT;r++) ps[r] += __shfl_xor(ps[r], off);
    }
    if (lane==0){
      #pragma unroll
      for (int r=0;r<NT;r++) redbuf[1][r][wvid] = ps[r];
    }
    __syncthreads();
    #pragma unroll
    for (int r=0;r<NT;r++){
      float s = redbuf[1][r][0]+redbuf[1][r][1]+redbuf[1][r][2]+redbuf[1][r][3];
      float inv = 1.0f / s;
      #pragma unroll
      for (int j=0;j<8;j++){
        float w = lg[r][j]*inv;
        wsumr[r][j] += w;
        wrow[r][tid + (j<<8)] = w;
      }
    }
    __syncthreads();
    {
      const int c = wvid, d = lane;
      float part[NT];
      #pragma unroll
      for (int r=0;r<NT;r++) part[r]=0.f;
      const size_t vofs = 2048 + (h<<6) + d;
      for (int mm = c<<9; mm < ((c+1)<<9); mm += 4){
        float wf[NT][4];
        #pragma unroll
        for (int r=0;r<NT;r++)
          *(float4*)wf[r] = *(const float4*)&wrow[r][mm];
        #pragma unroll
        for (int e=0;e<4;e++){
          float vvv = qkv[(size_t)(mm+e)*3072 + vofs];
          #pragma unroll
          for (int r=0;r<NT;r++) part[r] += wf[r][e]*vvv;
        }
      }
      #pragma unroll
      for (int r=0;r<NT;r++) attp[c][r][d] = part[r];
    }
    __syncthreads();
    {
      const int r = wvid, d = lane;
      float s = attp[0][r][d]+attp[1][r][d]+attp[2][r][d]+attp[3][r][d];
      att[(size_t)(n0+r)*DMODEL + (h<<6) + d] = s;
    }
  }
  #pragma unroll
  for (int r=0;r<NT;r++){
    #pragma unroll
    for (int j=0;j<8;j++)
      meanw[(size_t)(n0+r)*NTOK + tid + (j<<8)] = wsumr[r][j]*0.0625f;
  }
}

// =====================================================================================
extern "C" void kernel_launch(void* const* d_in, const int* in_sizes, int n_in,
                              void* d_out, int out_size, void* d_ws, size_t ws_size,
                              hipStream_t stream)
{
  const float* x     = (const float*)d_in[0];
  const float* Wqkv  = (const float*)d_in[3];
  const float* bqkv  = (const float*)d_in[4];
  const float* Wpq   = (const float*)d_in[5];
  const float* bpq   = (const float*)d_in[6];
  const float* Wpk   = (const float*)d_in[7];
  const float* bpk   = (const float*)d_in[8];
  const float* Wo    = (const float*)d_in[9];
  const float* bo    = (const float*)d_in[10];
  const float* gamma = (const float*)d_in[11];
  const float* beta  = (const float*)d_in[12];

  float* out0 = (float*)d_out;                   // ln      [2048,1024] f32
  float* out1 = out0 + (size_t)NTOK*DMODEL;      // mean_w  [2048,2048] f32

  const size_t sz_qkvb = (size_t)NTOK*3072*2;          // 12.6 MB
  const size_t sz_vt   = (size_t)NH*HD*NTOK*2;         //  4.2 MB
  const size_t sz_pq   = (size_t)NTOK*64*4;            //  0.5 MB
  const size_t sz_attb = (size_t)NTOK*DMODEL*2;        //  4.2 MB
  const size_t sz_wot  = (size_t)DMODEL*DMODEL*2;      //  2.1 MB
  const size_t sz_pbuf = (size_t)NH*NTOK*NTOK*2;       // 134.2 MB
  const size_t sz_invS = (size_t)NH*NTOK*4;            //  0.13 MB
  const size_t need_fast = sz_qkvb + sz_vt + 2*sz_pq + sz_attb + sz_wot + sz_pbuf + sz_invS;

  char* ws = (char*)d_ws;
  if (ws_size >= need_fast){
    u16*   qkvb = (u16*)ws;    ws += sz_qkvb;
    u16*   vt   = (u16*)ws;    ws += sz_vt;
    float* pqb  = (float*)ws;  ws += sz_pq;
    float* pkb  = (float*)ws;  ws += sz_pq;
    u16*   attb = (u16*)ws;    ws += sz_attb;
    u16*   Wot  = (u16*)ws;    ws += sz_wot;
    u16*   pbuf = (u16*)ws;    ws += sz_pbuf;
    float* invS = (float*)ws;  ws += sz_invS;
    // xb and Wt alias the (dead-until-attention) pbuf region
    u16*   xb   = pbuf;                                        // 4.2 MB
    u16*   Wt   = pbuf + (size_t)NTOK*DMODEL;                  // 6.3 MB

    k_points  <<<NTOK,          128, 0, stream>>>(x, Wpq, bpq, Wpk, bpk, pqb, pkb, xb);
    k_tcvt    <<<dim3(48,16),   256, 0, stream>>>(Wqkv, Wt, DMODEL, 3*DMODEL);
    k_tcvt    <<<dim3(16,16),   256, 0, stream>>>(Wo, Wot, DMODEL, DMODEL);
    k_gemm    <<<dim3(24,32),   256, 0, stream>>>(xb, Wt, bqkv, nullptr, qkvb, nullptr,
                                                  NTOK, 3*DMODEL, DMODEL, 1);
    k_vt      <<<dim3(32,16),   256, 0, stream>>>(qkvb, vt);
    k_attn_qk <<<dim3(64,16),   512, 0, stream>>>(qkvb, pqb, pkb, pbuf, invS);
    k_pv      <<<512,           256, 0, stream>>>(pbuf, vt, invS, attb);
    k_meanw   <<<NTOK,          256, 0, stream>>>(pbuf, invS, out1);
    k_gemm    <<<dim3(8,32),    256, 0, stream>>>(attb, Wot, bo, x, nullptr, out0,
                                                  NTOK, DMODEL, DMODEL, 0);
    k_ln      <<<NTOK,          256, 0, stream>>>(out0, gamma, beta, out0);
  } else {
    float* qkv = (float*)ws; ws += (size_t)NTOK*3072*4;
    float* pqb = (float*)ws; ws += sz_pq;
    float* pkb = (float*)ws; ws += sz_pq;
    float* att = (float*)ws; ws += (size_t)NTOK*DMODEL*4;

    k_qkv_f32 <<<dim3(256,3), 256, 0, stream>>>(x, Wqkv, bqkv, qkv);
    k_points  <<<NTOK,        128, 0, stream>>>(x, Wpq, bpq, Wpk, bpk, pqb, pkb, nullptr);
    k_attn_f32<<<NTOK/NT,     256, 0, stream>>>(qkv, pqb, pkb, att, out1);
    k_out_f32 <<<256,         512, 0, stream>>>(att, Wo, bo, x, out0);
    k_ln      <<<NTOK,        256, 0, stream>>>(out0, gamma, beta, out0);
  }
}

// Round 14
// 318.602 us; speedup vs baseline: 1.0015x; 1.0015x over previous
//
#include <hip/hip_runtime.h>

typedef unsigned short u16;
typedef unsigned int   u32;
typedef short bf16x8 __attribute__((ext_vector_type(8)));
typedef float f32x4  __attribute__((ext_vector_type(4)));
typedef unsigned int u32x4 __attribute__((ext_vector_type(4)));

#define NTOK   2048
#define DMODEL 1024
#define NH     16
#define HD     64

__device__ __forceinline__ u16 f2bf(float f){
  u32 x = __float_as_uint(f);
  return (u16)((x + 0x7fffu + ((x>>16)&1u)) >> 16);   // RNE
}
__device__ __forceinline__ void unpack8(uint4 u, float* f){
  f[0]=__uint_as_float(u.x<<16); f[1]=__uint_as_float(u.x&0xffff0000u);
  f[2]=__uint_as_float(u.y<<16); f[3]=__uint_as_float(u.y&0xffff0000u);
  f[4]=__uint_as_float(u.z<<16); f[5]=__uint_as_float(u.z&0xffff0000u);
  f[6]=__uint_as_float(u.w<<16); f[7]=__uint_as_float(u.w&0xffff0000u);
}
// pack 2 f32 -> 2 bf16 (RNE) in one VALU inst. lo = bf16(a), hi = bf16(b).
__device__ __forceinline__ u32 pk_bf16(float a, float b){
  u32 r;
  asm("v_cvt_pk_bf16_f32 %0, %1, %2" : "=v"(r) : "v"(a), "v"(b));
  return r;
}

// async global->LDS, 16B per lane. LDS dest must be wave-uniform base + lane*16 (linear).
#define GLOAD_LDS16(GP, LP) \
  __builtin_amdgcn_global_load_lds((__attribute__((address_space(1))) const void*)(GP), \
                                   (__attribute__((address_space(3))) void*)(LP), 16, 0, 0)

// =====================================================================================
// FAST PATH
// =====================================================================================

// W [K][N] fp32 -> Wt [N][K] bf16 (transpose + cvt). grid (N/64, K/64), block 256.
__global__ __launch_bounds__(256) void k_tcvt(const float* __restrict__ W, u16* __restrict__ Wt,
                                              int K, int N)
{
  const int tid = threadIdx.x;
  const int n0 = blockIdx.x * 64, k0 = blockIdx.y * 64;
  __shared__ float tileF[64*68];
  {
    int kk = tid >> 2, nseg = (tid & 3) * 16;
    const float* src = W + (size_t)(k0 + kk)*N + n0 + nseg;
    #pragma unroll
    for (int i=0;i<4;i++)
      *(float4*)&tileF[kk*68 + nseg + i*4] = *(const float4*)(src + i*4);
  }
  __syncthreads();
  {
    int n = tid >> 2, kseg = (tid & 3) * 16;
    u16 tmp[16];
    #pragma unroll
    for (int j=0;j<16;j++) tmp[j] = f2bf(tileF[(kseg + j)*68 + n]);
    uint4 o0, o1;
    o0.x=(u32)tmp[0]|((u32)tmp[1]<<16);  o0.y=(u32)tmp[2]|((u32)tmp[3]<<16);
    o0.z=(u32)tmp[4]|((u32)tmp[5]<<16);  o0.w=(u32)tmp[6]|((u32)tmp[7]<<16);
    o1.x=(u32)tmp[8]|((u32)tmp[9]<<16);  o1.y=(u32)tmp[10]|((u32)tmp[11]<<16);
    o1.z=(u32)tmp[12]|((u32)tmp[13]<<16);o1.w=(u32)tmp[14]|((u32)tmp[15]<<16);
    u16* dst = Wt + (size_t)(n0 + n)*K + k0 + kseg;
    *(uint4*)dst       = o0;
    *(uint4*)(dst + 8) = o1;
  }
}

// Generic bf16 MFMA GEMM: out[M][N] = A[M][K] @ Bt[N][K]^T + bias.
// M-tile 64, N-tile 128. global_load_lds width-16 staging, linear LDS tiles.
// qkvmode=1: out bf16, cols<1024 scaled by 1/8.  qkvmode=0: out fp32 = acc+bias+resid.
// grid (N/128, M/64), block 256 (4 waves, 2x2; wave owns 32 rows x 64 cols).
__global__ __launch_bounds__(256) void k_gemm(
    const u16* __restrict__ A, const u16* __restrict__ Bt,
    const float* __restrict__ bias, const float* __restrict__ resid,
    u16* __restrict__ outb, float* __restrict__ outf,
    int M, int N, int K, int qkvmode)
{
  const int tid  = threadIdx.x;
  const int lane = tid & 63, wv = tid >> 6;
  const int quad = lane >> 4, low = lane & 15;
  const int wm = wv >> 1, wn = wv & 1;
  const int m0 = blockIdx.y * 64, n0 = blockIdx.x * 128;

  __shared__ u16 Al[64*64];
  __shared__ u16 Bl[128*64];

  const f32x4 zz = {0.f,0.f,0.f,0.f};
  f32x4 acc[2][4];
  #pragma unroll
  for (int mt=0;mt<2;mt++)
    #pragma unroll
    for (int nt=0;nt<4;nt++) acc[mt][nt] = zz;

  for (int k0 = 0; k0 < K; k0 += 64){
    #pragma unroll
    for (int s = 0; s < 2; s++){
      int slot = tid + s*256;
      int row = slot >> 3, seg = (slot & 7) * 8;
      GLOAD_LDS16(A + (size_t)(m0+row)*K + k0 + seg, &Al[slot*8]);
    }
    #pragma unroll
    for (int s = 0; s < 4; s++){
      int slot = tid + s*256;
      int row = slot >> 3, seg = (slot & 7) * 8;
      GLOAD_LDS16(Bt + (size_t)(n0+row)*K + k0 + seg, &Bl[slot*8]);
    }
    __syncthreads();
    #pragma unroll
    for (int ks = 0; ks < 64; ks += 32){
      bf16x8 af[2], bfr[4];
      #pragma unroll
      for (int mt=0; mt<2; mt++)
        af[mt] = *(const bf16x8*)&Al[(wm*32 + mt*16 + low)*64 + ks + quad*8];
      #pragma unroll
      for (int nt=0; nt<4; nt++)
        bfr[nt] = *(const bf16x8*)&Bl[(wn*64 + nt*16 + low)*64 + ks + quad*8];
      #pragma unroll
      for (int mt=0; mt<2; mt++)
        #pragma unroll
        for (int nt=0; nt<4; nt++)
          // swapped operands: D row(quad*4+rg)=n, col(low)=m -> vectorized n-stores
          acc[mt][nt] = __builtin_amdgcn_mfma_f32_16x16x32_bf16(bfr[nt], af[mt], acc[mt][nt], 0,0,0);
    }
    __syncthreads();
  }

  #pragma unroll
  for (int mt=0; mt<2; mt++){
    int m = m0 + wm*32 + mt*16 + low;
    #pragma unroll
    for (int nt=0; nt<4; nt++){
      int n = n0 + wn*64 + nt*16 + quad*4;
      float4 bb = *(const float4*)(bias + n);
      float v0 = acc[mt][nt][0] + bb.x;
      float v1 = acc[mt][nt][1] + bb.y;
      float v2 = acc[mt][nt][2] + bb.z;
      float v3 = acc[mt][nt][3] + bb.w;
      if (qkvmode){
        float sc = (n < 1024) ? 0.125f : 1.0f;
        v0*=sc; v1*=sc; v2*=sc; v3*=sc;
        uint2 pk;
        pk.x = (u32)f2bf(v0) | ((u32)f2bf(v1)<<16);
        pk.y = (u32)f2bf(v2) | ((u32)f2bf(v3)<<16);
        *(uint2*)(outb + (size_t)m*N + n) = pk;
      } else {
        float4 xr = *(const float4*)(resid + (size_t)m*N + n);
        float4 o = {v0+xr.x, v1+xr.y, v2+xr.z, v3+xr.w};
        *(float4*)(outf + (size_t)m*N + n) = o;
      }
    }
  }
}

// transpose v: vt[h][d][m] bf16. grid (32 mtiles, 16 h), block 256.
__global__ __launch_bounds__(256) void k_vt(const u16* __restrict__ qkvb, u16* __restrict__ vt)
{
  const int m0 = blockIdx.x * 64;
  const int h  = blockIdx.y;
  const int tid = threadIdx.x;
  __shared__ u16 tile[64][72];
  {
    int row = tid >> 2, seg = (tid & 3) * 8;
    const u16* src = qkvb + (size_t)(m0 + row)*3072 + 2048 + h*64;
    *(uint4*)&tile[row][seg]      = *(const uint4*)(src + seg);
    *(uint4*)&tile[row][32 + seg] = *(const uint4*)(src + 32 + seg);
  }
  __syncthreads();
  {
    int d = tid >> 2, mseg = (tid & 3) * 16;
    __align__(16) u16 tmp[16];
    #pragma unroll
    for (int j=0;j<16;j++) tmp[j] = tile[mseg + j][d];
    u16* dst = vt + (size_t)(h*64 + d)*2048 + m0 + mseg;
    *(uint4*)dst       = *(uint4*)&tmp[0];
    *(uint4*)(dst + 8) = *(uint4*)&tmp[8];
  }
}

// QK + softmax-numerator kernel. grid (64 ntiles of 32 rows, 16 heads), block 512
// (8 waves; each wave owns a 256-key segment = 8 steps of 32 keys).
// Key-permuted loads (key = ks + (low>>2)*8 + kt*4 + (low&3)) so a lane's 8 p's
// across both kt are 8 CONTIGUOUS keys -> one 16B nt-store per row per step
// (nt-store verified r13: WRITE 172->140MB). bf16 packing via v_cvt_pk_bf16_f32.
// Constant-shift softmax: p = exp(l-48).
__global__ __launch_bounds__(512, 4) void k_attn_qk(
    const u16* __restrict__ qkvb,
    const float* __restrict__ pqb, const float* __restrict__ pkb,
    u16* __restrict__ pbuf, float* __restrict__ invSbuf)
{
  const int tid  = threadIdx.x;
  const int lane = tid & 63, wv = tid >> 6;
  const int quad = lane >> 4, low = lane & 15;
  const int n0 = blockIdx.x * 32;
  const int h  = blockIdx.y;

  __shared__ float rs[8][32];

  bf16x8 qf[2][2];
  #pragma unroll
  for (int rt=0; rt<2; rt++)
    #pragma unroll
    for (int df=0; df<2; df++)
      qf[rt][df] = *(const bf16x8*)(qkvb + (size_t)(n0 + rt*16 + low)*3072 + h*64 + df*32 + quad*8);

  // pq for this lane's own q-rows (rt*16+low)
  float4 pqr[2];
  #pragma unroll
  for (int rt=0; rt<2; rt++)
    pqr[rt] = *(const float4*)(pqb + (size_t)(n0 + rt*16 + low)*64 + h*4);

  const f32x4 zz = {0.f,0.f,0.f,0.f};
  float psum[2] = {0.f, 0.f};

  const int kperm = ((low>>2)<<3) + (low&3);   // + kt*4 per kt

  for (int step=0; step<8; step++){
    const int ks = (wv<<8) + (step<<5);
    u32x4 st0, st1;
    #pragma unroll
    for (int kt=0; kt<2; kt++){
      const u16* kbase = qkvb + (size_t)(ks + kperm + kt*4)*3072 + 1024 + h*64 + quad*8;
      bf16x8 kf0 = *(const bf16x8*)(kbase);
      bf16x8 kf1 = *(const bf16x8*)(kbase + 32);
      // swapped: D-row = key-slot (quad*4+rg) -> key ks + quad*8 + kt*4 + rg
      f32x4 a0 = zz, a1 = zz;
      a0 = __builtin_amdgcn_mfma_f32_16x16x32_bf16(kf0, qf[0][0], a0, 0,0,0);
      a0 = __builtin_amdgcn_mfma_f32_16x16x32_bf16(kf1, qf[0][1], a0, 0,0,0);
      a1 = __builtin_amdgcn_mfma_f32_16x16x32_bf16(kf0, qf[1][0], a1, 0,0,0);
      a1 = __builtin_amdgcn_mfma_f32_16x16x32_bf16(kf1, qf[1][1], a1, 0,0,0);
      float pv0[4], pv1[4];
      float s0 = 0.f, s1 = 0.f;
      #pragma unroll
      for (int rg=0; rg<4; rg++){
        float4 pk = *(const float4*)(pkb + (size_t)(ks + quad*8 + kt*4 + rg)*64 + h*4);
        float pkc = pk.w - 48.f;
        float4 pq0 = pqr[0], pq1 = pqr[1];
        float b0 = pq0.w + pkc - 2.f*(pq0.x*pk.x + pq0.y*pk.y + pq0.z*pk.z);
        float b1 = pq1.w + pkc - 2.f*(pq1.x*pk.x + pq1.y*pk.y + pq1.z*pk.z);
        pv0[rg] = __expf(a0[rg] + b0);
        pv1[rg] = __expf(a1[rg] + b1);
        s0 += pv0[rg]; s1 += pv1[rg];
      }
      psum[0] += s0; psum[1] += s1;
      u32 wa = pk_bf16(pv0[0], pv0[1]);
      u32 wb = pk_bf16(pv0[2], pv0[3]);
      u32 wc = pk_bf16(pv1[0], pv1[1]);
      u32 wd = pk_bf16(pv1[2], pv1[3]);
      if (kt == 0){ st0.x = wa; st0.y = wb; st1.x = wc; st1.y = wd; }
      else        { st0.z = wa; st0.w = wb; st1.z = wc; st1.w = wd; }
    }
    // row (n0+low) keys [ks+quad*8, ks+quad*8+8) -- 16B nt-store, 4 quads cover 64B
    __builtin_nontemporal_store(st0,
        (u32x4*)(pbuf + ((size_t)h*NTOK + n0 + low)*NTOK      + ks + quad*8));
    __builtin_nontemporal_store(st1,
        (u32x4*)(pbuf + ((size_t)h*NTOK + n0 + 16 + low)*NTOK + ks + quad*8));
  }

  // psum: lane-local over its keys; reduce across quads (lane bits 4,5)
  #pragma unroll
  for (int rt=0; rt<2; rt++){
    psum[rt] += __shfl_xor(psum[rt], 16);
    psum[rt] += __shfl_xor(psum[rt], 32);
  }
  if (quad == 0){
    rs[wv][low]      = psum[0];
    rs[wv][16 + low] = psum[1];
  }
  __syncthreads();
  if (tid < 32){
    float s = rs[0][tid] + rs[1][tid] + rs[2][tid] + rs[3][tid]
            + rs[4][tid] + rs[5][tid] + rs[6][tid] + rs[7][tid];
    invSbuf[(size_t)h*NTOK + n0 + tid] = 1.0f / s;
  }
}

// PV as a per-head GEMM: attb[m][h*64+n] = invS[h][m] * sum_k p[h][m][k] * vt[h][n][k].
// ROUND-11 VERSION (measured 59us; r13's P-in-register regressed to ~79us — scattered
// per-lane 16B loads lose to dense global_load_lds row staging, cf. m151).
// M-tile 64, BK=128, 1-D grid 512 (XCD-pinned: head h on XCD h&7), block 256 (4 waves),
// 2-phase double-buffer, XOR-swizzle both-sides (rule #21).
__global__ __launch_bounds__(256) void k_pv(
    const u16* __restrict__ pbuf, const u16* __restrict__ vt,
    const float* __restrict__ invSbuf, u16* __restrict__ attb)
{
  const int tid  = threadIdx.x;
  const int lane = tid & 63, wv = tid >> 6;
  const int quad = lane >> 4, low = lane & 15;
  // bid -> (head, m-tile): xcd = bid&7 hosts heads {xcd, xcd+8}; bijective.
  const int bid  = blockIdx.x;
  const int xcd  = bid & 7;
  const int slot = bid >> 3;                 // 0..63
  const int h    = xcd + ((slot >> 5) << 3); // slot<32 -> xcd, else xcd+8
  const int m0   = (slot & 31) * 64;

  __shared__ u16 Pl[2][64*128];
  __shared__ u16 Vl[2][64*128];

  const f32x4 zz = {0.f,0.f,0.f,0.f};
  f32x4 acc[4];
  #pragma unroll
  for (int nt=0;nt<4;nt++) acc[nt] = zz;

  const u16* pbase = pbuf + (size_t)h*NTOK*NTOK;
  const u16* vbase = vt   + (size_t)h*64*NTOK;

  const int rsw = (low & 7) << 3;   // read-side XOR (row&7 == low&7 for all row tiles)

  // per-thread staging coordinates (constant across iters)
  const int srow = tid >> 4;              // rows 0..15 (+16 per s)
  const int sseg = (tid & 15) * 8;
  const int ssw  = sseg ^ ((srow & 7) << 3);

#define PV_STAGE(PD, VD, K0)                                                         \
  { _Pragma("unroll")                                                                \
    for (int s = 0; s < 4; s++){                                                     \
      int slot_ = tid + s*256;                                                       \
      int row_  = srow + s*16;                                                       \
      GLOAD_LDS16(pbase + (size_t)(m0+row_)*NTOK + (K0) + ssw, (PD) + slot_*8);      \
      GLOAD_LDS16(vbase + (size_t)row_*NTOK + (K0) + ssw,      (VD) + slot_*8);      \
    } }

#define PV_COMPUTE(PC, VC)                                                           \
  { _Pragma("unroll")                                                                \
    for (int ks = 0; ks < 128; ks += 32){                                            \
      int col_ = (ks + quad*8) ^ rsw;                                                \
      bf16x8 af_ = *(const bf16x8*)&(PC)[(wv*16 + low)*128 + col_];                  \
      bf16x8 bfr_[4];                                                                \
      _Pragma("unroll")                                                              \
      for (int nt=0; nt<4; nt++)                                                     \
        bfr_[nt] = *(const bf16x8*)&(VC)[(nt*16 + low)*128 + col_];                  \
      _Pragma("unroll")                                                              \
      for (int nt=0; nt<4; nt++)                                                     \
        acc[nt] = __builtin_amdgcn_mfma_f32_16x16x32_bf16(bfr_[nt], af_, acc[nt], 0,0,0); \
    } }

  // prologue: stage tile 0, wait
  PV_STAGE(Pl[0], Vl[0], 0)
  __syncthreads();

  #pragma unroll 2
  for (int t = 0; t < 16; ++t){
    const int cur = t & 1;
    if (t < 15) PV_STAGE(Pl[cur^1], Vl[cur^1], (t+1)*128)
    PV_COMPUTE(Pl[cur], Vl[cur])
    __syncthreads();   // drains vmcnt(0): tile t+1 ready; buf[cur] free for t+2 stage
  }
#undef PV_STAGE
#undef PV_COMPUTE

  {
    int m = m0 + wv*16 + low;
    float inv = invSbuf[(size_t)h*NTOK + m];
    #pragma unroll
    for (int nt=0; nt<4; nt++){
      int n = nt*16 + quad*4;
      u16 t0 = f2bf(acc[nt][0]*inv);
      u16 t1 = f2bf(acc[nt][1]*inv);
      u16 t2 = f2bf(acc[nt][2]*inv);
      u16 t3 = f2bf(acc[nt][3]*inv);
      uint2 o; o.x = (u32)t0 | ((u32)t1<<16); o.y = (u32)t2 | ((u32)t3<<16);
      *(uint2*)(attb + (size_t)m*DMODEL + h*64 + n) = o;
    }
  }
}

// mean_w = (1/16) sum_h p[h][n][m] * invS[h][n]. grid 2048, block 256.
__global__ __launch_bounds__(256) void k_meanw(const u16* __restrict__ pbuf,
    const float* __restrict__ invSbuf, float* __restrict__ out1)
{
  const int n = blockIdx.x, tid = threadIdx.x;
  const int m0 = tid * 8;
  float acc[8];
  #pragma unroll
  for (int i=0;i<8;i++) acc[i]=0.f;
  for (int h=0; h<NH; h++){
    float inv = invSbuf[(size_t)h*NTOK + n] * 0.0625f;
    uint4 u = *(const uint4*)(pbuf + ((size_t)h*NTOK + n)*NTOK + m0);
    float pf[8]; unpack8(u, pf);
    #pragma unroll
    for (int i=0;i<8;i++) acc[i] += pf[i]*inv;
  }
  float4 a = {acc[0],acc[1],acc[2],acc[3]};
  float4 b = {acc[4],acc[5],acc[6],acc[7]};
  float* dst = out1 + (size_t)n*NTOK + m0;
  *(float4*)dst     = a;
  *(float4*)(dst+4) = b;
}

// =====================================================================================
// SHARED kernels
// =====================================================================================

// point projections + (fast path) fused x->bf16 conversion (xb != nullptr).
__global__ __launch_bounds__(128) void k_points(const float* __restrict__ x,
    const float* __restrict__ Wpq, const float* __restrict__ bpq,
    const float* __restrict__ Wpk, const float* __restrict__ bpk,
    float* __restrict__ pqb, float* __restrict__ pkb, u16* __restrict__ xb)
{
  const int n = blockIdx.x, tid = threadIdx.x;
  __shared__ float xr[1024];
  __shared__ float dots[96];
  float4 a = *(const float4*)(x + (size_t)n*DMODEL + tid*4);
  float4 b = *(const float4*)(x + (size_t)n*DMODEL + 512 + tid*4);
  *(float4*)&xr[tid*4]       = a;
  *(float4*)&xr[512 + tid*4] = b;
  if (xb){
    uint2 o1, o2;
    o1.x = (u32)f2bf(a.x) | ((u32)f2bf(a.y)<<16);
    o1.y = (u32)f2bf(a.z) | ((u32)f2bf(a.w)<<16);
    o2.x = (u32)f2bf(b.x) | ((u32)f2bf(b.y)<<16);
    o2.y = (u32)f2bf(b.z) | ((u32)f2bf(b.w)<<16);
    *(uint2*)(xb + (size_t)n*DMODEL + tid*4)       = o1;
    *(uint2*)(xb + (size_t)n*DMODEL + 512 + tid*4) = o2;
  }
  __syncthreads();
  if (tid < 96){
    const float* W  = (tid<48) ? Wpq : Wpk;
    const float* bb = (tid<48) ? bpq : bpk;
    int c = (tid<48) ? tid : tid-48;
    float acc = 0.f;
    for (int k=0;k<DMODEL;k++) acc += xr[k]*W[(size_t)k*48 + c];
    dots[tid] = acc + bb[c];
  }
  __syncthreads();
  if (tid < 96){
    int c = (tid<48)?tid:tid-48;
    int h = c/3, cc = c - h*3;
    float* o = (tid<48)?pqb:pkb;
    o[(size_t)n*64 + h*4 + cc] = dots[tid];
  }
  if (tid < 32){
    int h = tid & 15, isk = tid >> 4;
    int b0 = isk*48 + h*3;
    float a2=dots[b0], b2=dots[b0+1], c2=dots[b0+2];
    ((isk)?pkb:pqb)[(size_t)n*64 + h*4 + 3] = a2*a2+b2*b2+c2*c2;
  }
}

__global__ __launch_bounds__(256) void k_ln(float* __restrict__ res, const float* __restrict__ gamma,
    const float* __restrict__ beta, float* __restrict__ out)
{
  const int n = blockIdx.x, tid = threadIdx.x;
  const int lane = tid & 63, w = tid >> 6;
  __shared__ float red[2][4];
  float4 v = *(const float4*)(res + (size_t)n*DMODEL + tid*4);
  float s  = v.x+v.y+v.z+v.w;
  float s2 = v.x*v.x+v.y*v.y+v.z*v.z+v.w*v.w;
  #pragma unroll
  for (int off=32; off>0; off>>=1){ s += __shfl_xor(s, off); s2 += __shfl_xor(s2, off); }
  if (lane==0){ red[0][w]=s; red[1][w]=s2; }
  __syncthreads();
  float mean = (red[0][0]+red[0][1]+red[0][2]+red[0][3]) * (1.f/1024.f);
  float m2   = (red[1][0]+red[1][1]+red[1][2]+red[1][3]) * (1.f/1024.f);
  float rs = rsqrtf(m2 - mean*mean + 1e-5f);
  float4 g = *(const float4*)(gamma + tid*4);
  float4 b = *(const float4*)(beta  + tid*4);
  float4 o;
  o.x = (v.x-mean)*rs*g.x + b.x;
  o.y = (v.y-mean)*rs*g.y + b.y;
  o.z = (v.z-mean)*rs*g.z + b.z;
  o.w = (v.w-mean)*rs*g.w + b.w;
  *(float4*)(out + (size_t)n*DMODEL + tid*4) = o;
}

// =====================================================================================
// FALLBACK PATH (fp32, small workspace)
// =====================================================================================

__global__ __launch_bounds__(256) void k_qkv_f32(const float* __restrict__ x, const float* __restrict__ W,
        const float* __restrict__ bias, float* __restrict__ qkv)
{
  const int tid = threadIdx.x;
  const int n0  = blockIdx.x * 8;
  const int c0  = blockIdx.y * 1024 + tid * 4;
  __shared__ float xs[8][1024];
  for (int i = tid; i < 2048; i += 256){
    int r = i >> 8, cc = (i & 255) << 2;
    *(float4*)&xs[r][cc] = *(const float4*)(x + (size_t)(n0 + r)*DMODEL + cc);
  }
  __syncthreads();
  float acc[8][4];
  #pragma unroll
  for (int r=0;r<8;r++){ acc[r][0]=0.f;acc[r][1]=0.f;acc[r][2]=0.f;acc[r][3]=0.f; }
  for (int k=0;k<DMODEL;k+=4){
    float4 xr[8];
    #pragma unroll
    for (int r=0;r<8;r++) xr[r] = *(const float4*)&xs[r][k];
    #pragma unroll
    for (int kk=0;kk<4;kk++){
      float4 wf = *(const float4*)(W + (size_t)(k+kk)*3072 + c0);
      #pragma unroll
      for (int r=0;r<8;r++){
        float xv = ((const float*)&xr[r])[kk];
        acc[r][0] += xv*wf.x; acc[r][1] += xv*wf.y;
        acc[r][2] += xv*wf.z; acc[r][3] += xv*wf.w;
      }
    }
  }
  float4 bb = *(const float4*)(bias + c0);
  const float sc = (blockIdx.y == 0) ? 0.125f : 1.0f;
  #pragma unroll
  for (int r=0;r<8;r++){
    float4 o;
    o.x = (acc[r][0]+bb.x)*sc; o.y = (acc[r][1]+bb.y)*sc;
    o.z = (acc[r][2]+bb.z)*sc; o.w = (acc[r][3]+bb.w)*sc;
    *(float4*)(qkv + (size_t)(n0+r)*3072 + c0) = o;
  }
}

__global__ __launch_bounds__(512) void k_out_f32(const float* __restrict__ att, const float* __restrict__ Wo,
    const float* __restrict__ bo, const float* __restrict__ x, float* __restrict__ res)
{
  const int tid = threadIdx.x;
  const int n0 = blockIdx.x * 8;
  const int c0 = tid * 2;
  __shared__ float sA[8][1024];
  for (int i = tid; i < 2048; i += 512){
    int r = i >> 8, cc = (i & 255) << 2;
    *(float4*)&sA[r][cc] = *(const float4*)(att + (size_t)(n0+r)*DMODEL + cc);
  }
  __syncthreads();
  float acc[8][2];
  #pragma unroll
  for (int r=0;r<8;r++){ acc[r][0]=0.f; acc[r][1]=0.f; }
  for (int k=0;k<DMODEL;k+=4){
    float4 ar[8];
    #pragma unroll
    for (int r=0;r<8;r++) ar[r] = *(const float4*)&sA[r][k];
    #pragma unroll
    for (int kk=0;kk<4;kk++){
      float2 wf = *(const float2*)(Wo + (size_t)(k+kk)*DMODEL + c0);
      #pragma unroll
      for (int r=0;r<8;r++){
        float av = ((const float*)&ar[r])[kk];
        acc[r][0] += av*wf.x; acc[r][1] += av*wf.y;
      }
    }
  }
  float2 bb = *(const float2*)(bo + c0);
  #pragma unroll
  for (int r=0;r<8;r++){
    float2 xf = *(const float2*)(x + (size_t)(n0+r)*DMODEL + c0);
    float2 o; o.x = acc[r][0]+bb.x+xf.x; o.y = acc[r][1]+bb.y+xf.y;
    *(float2*)(res + (size_t)(n0+r)*DMODEL + c0) = o;
  }
}

#define NT 4
__global__ __launch_bounds__(256) void k_attn_f32(const float* __restrict__ qkv,
    const float* __restrict__ pqb, const float* __restrict__ pkb,
    float* __restrict__ att, float* __restrict__ meanw)
{
  const int tid = threadIdx.x;
  const int lane = tid & 63, wvid = tid >> 6;
  const int n0 = blockIdx.x * NT;
  __shared__ __align__(16) float wrow[NT][NTOK];
  __shared__ float attp[4][NT][HD];
  __shared__ float redbuf[2][NT][4];
  float wsumr[NT][8];
  #pragma unroll
  for (int r=0;r<NT;r++){
    #pragma unroll
    for (int j=0;j<8;j++) wsumr[r][j]=0.f;
  }
  for (int h=0; h<NH; h++){
    __syncthreads();
    float lg[NT][8];
    {
      float pq0[NT],pq1[NT],pq2[NT],pq3[NT];
      #pragma unroll
      for (int r=0;r<NT;r++){
        const float* pq = pqb + (size_t)(n0+r)*64 + (h<<2);
        pq0[r]=pq[0]; pq1[r]=pq[1]; pq2[r]=pq[2]; pq3[r]=pq[3];
      }
      #pragma unroll
      for (int j=0;j<8;j++){
        int m = tid + (j<<8);
        float4 p = *(const float4*)(pkb + (size_t)m*64 + (h<<2));
        #pragma unroll
        for (int r=0;r<NT;r++)
          lg[r][j] = pq3[r] + p.w - 2.f*(pq0[r]*p.x + pq1[r]*p.y + pq2[r]*p.z);
      }
    }
    for (int c8=0;c8<8;c8++){
      float qv[NT][8];
      #pragma unroll
      for (int r=0;r<NT;r++){
        const float4* qp = (const float4*)(qkv + (size_t)(n0+r)*3072 + (h<<6) + (c8<<3));
        float4 a = qp[0], b = qp[1];
        qv[r][0]=a.x;qv[r][1]=a.y;qv[r][2]=a.z;qv[r][3]=a.w;
        qv[r][4]=b.x;qv[r][5]=b.y;qv[r][6]=b.z;qv[r][7]=b.w;
      }
      #pragma unroll
      for (int j=0;j<8;j++){
        int m = tid + (j<<8);
        const float* kp = qkv + (size_t)m*3072 + 1024 + (h<<6) + (c8<<3);
        float4 k0 = *(const float4*)kp, k1 = *(const float4*)(kp+4);
        #pragma unroll
        for (int r=0;r<NT;r++){
          lg[r][j] += qv[r][0]*k0.x+qv[r][1]*k0.y+qv[r][2]*k0.z+qv[r][3]*k0.w
                    + qv[r][4]*k1.x+qv[r][5]*k1.y+qv[r][6]*k1.z+qv[r][7]*k1.w;
        }
      }
    }
    float mx[NT];
    #pragma unroll
    for (int r=0;r<NT;r++){
      float m0 = lg[r][0];
      #pragma unroll
      for (int j=1;j<8;j++) m0 = fmaxf(m0, lg[r][j]);
      mx[r]=m0;
    }
    #pragma unroll
    for (int off=32; off>0; off>>=1){
      #pragma unroll
      for (int r=0;r<NT;r++) mx[r] = fmaxf(mx[r], __shfl_xor(mx[r], off));
    }
    if (lane==0){
      #pragma unroll
      for (int r=0;r<NT;r++) redbuf[0][r][wvid] = mx[r];
    }
    __syncthreads();
    float ps[NT];
    #pragma unroll
    for (int r=0;r<NT;r++){
      float bm = fmaxf(fmaxf(redbuf[0][r][0],redbuf[0][r][1]),
                       fmaxf(redbuf[0][r][2],redbuf[0][r][3]));
      float s = 0.f;
      #pragma unroll
      for (int j=0;j<8;j++){ float p = __expf(lg[r][j]-bm); lg[r][j]=p; s+=p; }
      ps[r]=s;
    }
    #pragma unroll
    for (int off=32; off>0; off>>=1){
      #pragma unroll
      for (int r=0;r<NT;r++) ps[r] += __shfl_xor(ps[r], off);
    }
    if (lane==0){
      #pragma unroll
      for (int r=0;r<NT;r++) redbuf[1][r][wvid] = ps[r];
    }
    __syncthreads();
    #pragma unroll
    for (int r=0;r<NT;r++){
      float s = redbuf[1][r][0]+redbuf[1][r][1]+redbuf[1][r][2]+redbuf[1][r][3];
      float inv = 1.0f / s;
      #pragma unroll
      for (int j=0;j<8;j++){
        float w = lg[r][j]*inv;
        wsumr[r][j] += w;
        wrow[r][tid + (j<<8)] = w;
      }
    }
    __syncthreads();
    {
      const int c = wvid, d = lane;
      float part[NT];
      #pragma unroll
      for (int r=0;r<NT;r++) part[r]=0.f;
      const size_t vofs = 2048 + (h<<6) + d;
      for (int mm = c<<9; mm < ((c+1)<<9); mm += 4){
        float wf[NT][4];
        #pragma unroll
        for (int r=0;r<NT;r++)
          *(float4*)wf[r] = *(const float4*)&wrow[r][mm];
        #pragma unroll
        for (int e=0;e<4;e++){
          float vvv = qkv[(size_t)(mm+e)*3072 + vofs];
          #pragma unroll
          for (int r=0;r<NT;r++) part[r] += wf[r][e]*vvv;
        }
      }
      #pragma unroll
      for (int r=0;r<NT;r++) attp[c][r][d] = part[r];
    }
    __syncthreads();
    {
      const int r = wvid, d = lane;
      float s = attp[0][r][d]+attp[1][r][d]+attp[2][r][d]+attp[3][r][d];
      att[(size_t)(n0+r)*DMODEL + (h<<6) + d] = s;
    }
  }
  #pragma unroll
  for (int r=0;r<NT;r++){
    #pragma unroll
    for (int j=0;j<8;j++)
      meanw[(size_t)(n0+r)*NTOK + tid + (j<<8)] = wsumr[r][j]*0.0625f;
  }
}

// =====================================================================================
extern "C" void kernel_launch(void* const* d_in, const int* in_sizes, int n_in,
                              void* d_out, int out_size, void* d_ws, size_t ws_size,
                              hipStream_t stream)
{
  const float* x     = (const float*)d_in[0];
  const float* Wqkv  = (const float*)d_in[3];
  const float* bqkv  = (const float*)d_in[4];
  const float* Wpq   = (const float*)d_in[5];
  const float* bpq   = (const float*)d_in[6];
  const float* Wpk   = (const float*)d_in[7];
  const float* bpk   = (const float*)d_in[8];
  const float* Wo    = (const float*)d_in[9];
  const float* bo    = (const float*)d_in[10];
  const float* gamma = (const float*)d_in[11];
  const float* beta  = (const float*)d_in[12];

  float* out0 = (float*)d_out;                   // ln      [2048,1024] f32
  float* out1 = out0 + (size_t)NTOK*DMODEL;      // mean_w  [2048,2048] f32

  const size_t sz_qkvb = (size_t)NTOK*3072*2;          // 12.6 MB
  const size_t sz_vt   = (size_t)NH*HD*NTOK*2;         //  4.2 MB
  const size_t sz_pq   = (size_t)NTOK*64*4;            //  0.5 MB
  const size_t sz_attb = (size_t)NTOK*DMODEL*2;        //  4.2 MB
  const size_t sz_wot  = (size_t)DMODEL*DMODEL*2;      //  2.1 MB
  const size_t sz_pbuf = (size_t)NH*NTOK*NTOK*2;       // 134.2 MB
  const size_t sz_invS = (size_t)NH*NTOK*4;            //  0.13 MB
  const size_t need_fast = sz_qkvb + sz_vt + 2*sz_pq + sz_attb + sz_wot + sz_pbuf + sz_invS;

  char* ws = (char*)d_ws;
  if (ws_size >= need_fast){
    u16*   qkvb = (u16*)ws;    ws += sz_qkvb;
    u16*   vt   = (u16*)ws;    ws += sz_vt;
    float* pqb  = (float*)ws;  ws += sz_pq;
    float* pkb  = (float*)ws;  ws += sz_pq;
    u16*   attb = (u16*)ws;    ws += sz_attb;
    u16*   Wot  = (u16*)ws;    ws += sz_wot;
    u16*   pbuf = (u16*)ws;    ws += sz_pbuf;
    float* invS = (float*)ws;  ws += sz_invS;
    // xb and Wt alias the (dead-until-attention) pbuf region
    u16*   xb   = pbuf;                                        // 4.2 MB
    u16*   Wt   = pbuf + (size_t)NTOK*DMODEL;                  // 6.3 MB

    k_points  <<<NTOK,          128, 0, stream>>>(x, Wpq, bpq, Wpk, bpk, pqb, pkb, xb);
    k_tcvt    <<<dim3(48,16),   256, 0, stream>>>(Wqkv, Wt, DMODEL, 3*DMODEL);
    k_tcvt    <<<dim3(16,16),   256, 0, stream>>>(Wo, Wot, DMODEL, DMODEL);
    k_gemm    <<<dim3(24,32),   256, 0, stream>>>(xb, Wt, bqkv, nullptr, qkvb, nullptr,
                                                  NTOK, 3*DMODEL, DMODEL, 1);
    k_vt      <<<dim3(32,16),   256, 0, stream>>>(qkvb, vt);
    k_attn_qk <<<dim3(64,16),   512, 0, stream>>>(qkvb, pqb, pkb, pbuf, invS);
    k_pv      <<<512,           256, 0, stream>>>(pbuf, vt, invS, attb);
    k_meanw   <<<NTOK,          256, 0, stream>>>(pbuf, invS, out1);
    k_gemm    <<<dim3(8,32),    256, 0, stream>>>(attb, Wot, bo, x, nullptr, out0,
                                                  NTOK, DMODEL, DMODEL, 0);
    k_ln      <<<NTOK,          256, 0, stream>>>(out0, gamma, beta, out0);
  } else {
    float* qkv = (float*)ws; ws += (size_t)NTOK*3072*4;
    float* pqb = (float*)ws; ws += sz_pq;
    float* pkb = (float*)ws; ws += sz_pq;
    float* att = (float*)ws; ws += (size_t)NTOK*DMODEL*4;

    k_qkv_f32 <<<dim3(256,3), 256, 0, stream>>>(x, Wqkv, bqkv, qkv);
    k_points  <<<NTOK,        128, 0, stream>>>(x, Wpq, bpq, Wpk, bpk, pqb, pkb, nullptr);
    k_attn_f32<<<NTOK/NT,     256, 0, stream>>>(qkv, pqb, pkb, att, out1);
    k_out_f32 <<<256,         512, 0, stream>>>(att, Wo, bo, x, out0);
    k_ln      <<<NTOK,        256, 0, stream>>>(out0, gamma, beta, out0);
  }
}

// Round 15
// 301.336 us; speedup vs baseline: 1.0589x; 1.0573x over previous
//
#include <hip/hip_runtime.h>

typedef unsigned short u16;
typedef unsigned int   u32;
typedef short bf16x8 __attribute__((ext_vector_type(8)));
typedef float f32x4  __attribute__((ext_vector_type(4)));
typedef unsigned int u32x4 __attribute__((ext_vector_type(4)));

#define NTOK   2048
#define DMODEL 1024
#define NH     16
#define HD     64

__device__ __forceinline__ u16 f2bf(float f){
  u32 x = __float_as_uint(f);
  return (u16)((x + 0x7fffu + ((x>>16)&1u)) >> 16);   // RNE
}
__device__ __forceinline__ void unpack8(uint4 u, float* f){
  f[0]=__uint_as_float(u.x<<16); f[1]=__uint_as_float(u.x&0xffff0000u);
  f[2]=__uint_as_float(u.y<<16); f[3]=__uint_as_float(u.y&0xffff0000u);
  f[4]=__uint_as_float(u.z<<16); f[5]=__uint_as_float(u.z&0xffff0000u);
  f[6]=__uint_as_float(u.w<<16); f[7]=__uint_as_float(u.w&0xffff0000u);
}
// pack 2 f32 -> 2 bf16 (RNE) in one VALU inst. lo = bf16(a), hi = bf16(b).
__device__ __forceinline__ u32 pk_bf16(float a, float b){
  u32 r;
  asm("v_cvt_pk_bf16_f32 %0, %1, %2" : "=v"(r) : "v"(a), "v"(b));
  return r;
}

// async global->LDS, 16B per lane. LDS dest must be wave-uniform base + lane*16 (linear).
#define GLOAD_LDS16(GP, LP) \
  __builtin_amdgcn_global_load_lds((__attribute__((address_space(1))) const void*)(GP), \
                                   (__attribute__((address_space(3))) void*)(LP), 16, 0, 0)

// =====================================================================================
// FAST PATH
// =====================================================================================

// W [K][N] fp32 -> Wt [N][K] bf16 (transpose + cvt). grid (N/64, K/64), block 256.
__global__ __launch_bounds__(256) void k_tcvt(const float* __restrict__ W, u16* __restrict__ Wt,
                                              int K, int N)
{
  const int tid = threadIdx.x;
  const int n0 = blockIdx.x * 64, k0 = blockIdx.y * 64;
  __shared__ float tileF[64*68];
  {
    int kk = tid >> 2, nseg = (tid & 3) * 16;
    const float* src = W + (size_t)(k0 + kk)*N + n0 + nseg;
    #pragma unroll
    for (int i=0;i<4;i++)
      *(float4*)&tileF[kk*68 + nseg + i*4] = *(const float4*)(src + i*4);
  }
  __syncthreads();
  {
    int n = tid >> 2, kseg = (tid & 3) * 16;
    u16 tmp[16];
    #pragma unroll
    for (int j=0;j<16;j++) tmp[j] = f2bf(tileF[(kseg + j)*68 + n]);
    uint4 o0, o1;
    o0.x=(u32)tmp[0]|((u32)tmp[1]<<16);  o0.y=(u32)tmp[2]|((u32)tmp[3]<<16);
    o0.z=(u32)tmp[4]|((u32)tmp[5]<<16);  o0.w=(u32)tmp[6]|((u32)tmp[7]<<16);
    o1.x=(u32)tmp[8]|((u32)tmp[9]<<16);  o1.y=(u32)tmp[10]|((u32)tmp[11]<<16);
    o1.z=(u32)tmp[12]|((u32)tmp[13]<<16);o1.w=(u32)tmp[14]|((u32)tmp[15]<<16);
    u16* dst = Wt + (size_t)(n0 + n)*K + k0 + kseg;
    *(uint4*)dst       = o0;
    *(uint4*)(dst + 8) = o1;
  }
}

// Generic bf16 MFMA GEMM: out[M][N] = A[M][K] @ Bt[N][K]^T + bias.
// M-tile 64, N-tile 128. global_load_lds width-16 staging, linear LDS tiles.
// qkvmode=1: out bf16, cols<1024 scaled by 1/8.  qkvmode=0: out fp32 = acc+bias+resid.
// grid (N/128, M/64), block 256 (4 waves, 2x2; wave owns 32 rows x 64 cols).
__global__ __launch_bounds__(256) void k_gemm(
    const u16* __restrict__ A, const u16* __restrict__ Bt,
    const float* __restrict__ bias, const float* __restrict__ resid,
    u16* __restrict__ outb, float* __restrict__ outf,
    int M, int N, int K, int qkvmode)
{
  const int tid  = threadIdx.x;
  const int lane = tid & 63, wv = tid >> 6;
  const int quad = lane >> 4, low = lane & 15;
  const int wm = wv >> 1, wn = wv & 1;
  const int m0 = blockIdx.y * 64, n0 = blockIdx.x * 128;

  __shared__ u16 Al[64*64];
  __shared__ u16 Bl[128*64];

  const f32x4 zz = {0.f,0.f,0.f,0.f};
  f32x4 acc[2][4];
  #pragma unroll
  for (int mt=0;mt<2;mt++)
    #pragma unroll
    for (int nt=0;nt<4;nt++) acc[mt][nt] = zz;

  for (int k0 = 0; k0 < K; k0 += 64){
    #pragma unroll
    for (int s = 0; s < 2; s++){
      int slot = tid + s*256;
      int row = slot >> 3, seg = (slot & 7) * 8;
      GLOAD_LDS16(A + (size_t)(m0+row)*K + k0 + seg, &Al[slot*8]);
    }
    #pragma unroll
    for (int s = 0; s < 4; s++){
      int slot = tid + s*256;
      int row = slot >> 3, seg = (slot & 7) * 8;
      GLOAD_LDS16(Bt + (size_t)(n0+row)*K + k0 + seg, &Bl[slot*8]);
    }
    __syncthreads();
    #pragma unroll
    for (int ks = 0; ks < 64; ks += 32){
      bf16x8 af[2], bfr[4];
      #pragma unroll
      for (int mt=0; mt<2; mt++)
        af[mt] = *(const bf16x8*)&Al[(wm*32 + mt*16 + low)*64 + ks + quad*8];
      #pragma unroll
      for (int nt=0; nt<4; nt++)
        bfr[nt] = *(const bf16x8*)&Bl[(wn*64 + nt*16 + low)*64 + ks + quad*8];
      #pragma unroll
      for (int mt=0; mt<2; mt++)
        #pragma unroll
        for (int nt=0; nt<4; nt++)
          // swapped operands: D row(quad*4+rg)=n, col(low)=m -> vectorized n-stores
          acc[mt][nt] = __builtin_amdgcn_mfma_f32_16x16x32_bf16(bfr[nt], af[mt], acc[mt][nt], 0,0,0);
    }
    __syncthreads();
  }

  #pragma unroll
  for (int mt=0; mt<2; mt++){
    int m = m0 + wm*32 + mt*16 + low;
    #pragma unroll
    for (int nt=0; nt<4; nt++){
      int n = n0 + wn*64 + nt*16 + quad*4;
      float4 bb = *(const float4*)(bias + n);
      float v0 = acc[mt][nt][0] + bb.x;
      float v1 = acc[mt][nt][1] + bb.y;
      float v2 = acc[mt][nt][2] + bb.z;
      float v3 = acc[mt][nt][3] + bb.w;
      if (qkvmode){
        float sc = (n < 1024) ? 0.125f : 1.0f;
        v0*=sc; v1*=sc; v2*=sc; v3*=sc;
        uint2 pk;
        pk.x = (u32)f2bf(v0) | ((u32)f2bf(v1)<<16);
        pk.y = (u32)f2bf(v2) | ((u32)f2bf(v3)<<16);
        *(uint2*)(outb + (size_t)m*N + n) = pk;
      } else {
        float4 xr = *(const float4*)(resid + (size_t)m*N + n);
        float4 o = {v0+xr.x, v1+xr.y, v2+xr.z, v3+xr.w};
        *(float4*)(outf + (size_t)m*N + n) = o;
      }
    }
  }
}

// transpose v: vt[h][d][m] bf16. grid (32 mtiles, 16 h), block 256.
__global__ __launch_bounds__(256) void k_vt(const u16* __restrict__ qkvb, u16* __restrict__ vt)
{
  const int m0 = blockIdx.x * 64;
  const int h  = blockIdx.y;
  const int tid = threadIdx.x;
  __shared__ u16 tile[64][72];
  {
    int row = tid >> 2, seg = (tid & 3) * 8;
    const u16* src = qkvb + (size_t)(m0 + row)*3072 + 2048 + h*64;
    *(uint4*)&tile[row][seg]      = *(const uint4*)(src + seg);
    *(uint4*)&tile[row][32 + seg] = *(const uint4*)(src + 32 + seg);
  }
  __syncthreads();
  {
    int d = tid >> 2, mseg = (tid & 3) * 16;
    __align__(16) u16 tmp[16];
    #pragma unroll
    for (int j=0;j<16;j++) tmp[j] = tile[mseg + j][d];
    u16* dst = vt + (size_t)(h*64 + d)*2048 + m0 + mseg;
    *(uint4*)dst       = *(uint4*)&tmp[0];
    *(uint4*)(dst + 8) = *(uint4*)&tmp[8];
  }
}

// QK + softmax-numerator kernel. grid (64 ntiles of 32 rows, 16 heads), block 512
// (8 waves; each wave owns a 256-key segment = 8 steps of 32 keys).
// Key-permuted loads (key = ks + (low>>2)*8 + kt*4 + (low&3)) so a lane's 8 p's
// across both kt are 8 CONTIGUOUS keys -> one 16B store per row per step.
// REGULAR stores (r13/r14 nt-store saved 1.6us in-kernel but cost ~15us downstream:
// pv/meanw lost L2 write-to-read forwarding on the P stream).
// bf16 packing via v_cvt_pk_bf16_f32. Constant-shift softmax: p = exp(l-48).
__global__ __launch_bounds__(512, 4) void k_attn_qk(
    const u16* __restrict__ qkvb,
    const float* __restrict__ pqb, const float* __restrict__ pkb,
    u16* __restrict__ pbuf, float* __restrict__ invSbuf)
{
  const int tid  = threadIdx.x;
  const int lane = tid & 63, wv = tid >> 6;
  const int quad = lane >> 4, low = lane & 15;
  const int n0 = blockIdx.x * 32;
  const int h  = blockIdx.y;

  __shared__ float rs[8][32];

  bf16x8 qf[2][2];
  #pragma unroll
  for (int rt=0; rt<2; rt++)
    #pragma unroll
    for (int df=0; df<2; df++)
      qf[rt][df] = *(const bf16x8*)(qkvb + (size_t)(n0 + rt*16 + low)*3072 + h*64 + df*32 + quad*8);

  // pq for this lane's own q-rows (rt*16+low)
  float4 pqr[2];
  #pragma unroll
  for (int rt=0; rt<2; rt++)
    pqr[rt] = *(const float4*)(pqb + (size_t)(n0 + rt*16 + low)*64 + h*4);

  const f32x4 zz = {0.f,0.f,0.f,0.f};
  float psum[2] = {0.f, 0.f};

  const int kperm = ((low>>2)<<3) + (low&3);   // + kt*4 per kt

  for (int step=0; step<8; step++){
    const int ks = (wv<<8) + (step<<5);
    u32x4 st0, st1;
    #pragma unroll
    for (int kt=0; kt<2; kt++){
      const u16* kbase = qkvb + (size_t)(ks + kperm + kt*4)*3072 + 1024 + h*64 + quad*8;
      bf16x8 kf0 = *(const bf16x8*)(kbase);
      bf16x8 kf1 = *(const bf16x8*)(kbase + 32);
      // swapped: D-row = key-slot (quad*4+rg) -> key ks + quad*8 + kt*4 + rg
      f32x4 a0 = zz, a1 = zz;
      a0 = __builtin_amdgcn_mfma_f32_16x16x32_bf16(kf0, qf[0][0], a0, 0,0,0);
      a0 = __builtin_amdgcn_mfma_f32_16x16x32_bf16(kf1, qf[0][1], a0, 0,0,0);
      a1 = __builtin_amdgcn_mfma_f32_16x16x32_bf16(kf0, qf[1][0], a1, 0,0,0);
      a1 = __builtin_amdgcn_mfma_f32_16x16x32_bf16(kf1, qf[1][1], a1, 0,0,0);
      float pv0[4], pv1[4];
      float s0 = 0.f, s1 = 0.f;
      #pragma unroll
      for (int rg=0; rg<4; rg++){
        float4 pk = *(const float4*)(pkb + (size_t)(ks + quad*8 + kt*4 + rg)*64 + h*4);
        float pkc = pk.w - 48.f;
        float4 pq0 = pqr[0], pq1 = pqr[1];
        float b0 = pq0.w + pkc - 2.f*(pq0.x*pk.x + pq0.y*pk.y + pq0.z*pk.z);
        float b1 = pq1.w + pkc - 2.f*(pq1.x*pk.x + pq1.y*pk.y + pq1.z*pk.z);
        pv0[rg] = __expf(a0[rg] + b0);
        pv1[rg] = __expf(a1[rg] + b1);
        s0 += pv0[rg]; s1 += pv1[rg];
      }
      psum[0] += s0; psum[1] += s1;
      u32 wa = pk_bf16(pv0[0], pv0[1]);
      u32 wb = pk_bf16(pv0[2], pv0[3]);
      u32 wc = pk_bf16(pv1[0], pv1[1]);
      u32 wd = pk_bf16(pv1[2], pv1[3]);
      if (kt == 0){ st0.x = wa; st0.y = wb; st1.x = wc; st1.y = wd; }
      else        { st0.z = wa; st0.w = wb; st1.z = wc; st1.w = wd; }
    }
    // row (n0+low) keys [ks+quad*8, ks+quad*8+8) -- 16B store, 4 quads cover 64B
    *(u32x4*)(pbuf + ((size_t)h*NTOK + n0 + low)*NTOK      + ks + quad*8) = st0;
    *(u32x4*)(pbuf + ((size_t)h*NTOK + n0 + 16 + low)*NTOK + ks + quad*8) = st1;
  }

  // psum: lane-local over its keys; reduce across quads (lane bits 4,5)
  #pragma unroll
  for (int rt=0; rt<2; rt++){
    psum[rt] += __shfl_xor(psum[rt], 16);
    psum[rt] += __shfl_xor(psum[rt], 32);
  }
  if (quad == 0){
    rs[wv][low]      = psum[0];
    rs[wv][16 + low] = psum[1];
  }
  __syncthreads();
  if (tid < 32){
    float s = rs[0][tid] + rs[1][tid] + rs[2][tid] + rs[3][tid]
            + rs[4][tid] + rs[5][tid] + rs[6][tid] + rs[7][tid];
    invSbuf[(size_t)h*NTOK + n0 + tid] = 1.0f / s;
  }
}

// PV as a per-head GEMM: attb[m][h*64+n] = invS[h][m] * sum_k p[h][m][k] * vt[h][n][k].
// ROUND-11 VERSION (measured 59us). M-tile 64, BK=128, 1-D grid 512 (XCD-pinned:
// head h on XCD h&7), block 256 (4 waves), 2-phase double-buffer, XOR-swizzle
// both-sides (rule #21).
__global__ __launch_bounds__(256) void k_pv(
    const u16* __restrict__ pbuf, const u16* __restrict__ vt,
    const float* __restrict__ invSbuf, u16* __restrict__ attb)
{
  const int tid  = threadIdx.x;
  const int lane = tid & 63, wv = tid >> 6;
  const int quad = lane >> 4, low = lane & 15;
  // bid -> (head, m-tile): xcd = bid&7 hosts heads {xcd, xcd+8}; bijective.
  const int bid  = blockIdx.x;
  const int xcd  = bid & 7;
  const int slot = bid >> 3;                 // 0..63
  const int h    = xcd + ((slot >> 5) << 3); // slot<32 -> xcd, else xcd+8
  const int m0   = (slot & 31) * 64;

  __shared__ u16 Pl[2][64*128];
  __shared__ u16 Vl[2][64*128];

  const f32x4 zz = {0.f,0.f,0.f,0.f};
  f32x4 acc[4];
  #pragma unroll
  for (int nt=0;nt<4;nt++) acc[nt] = zz;

  const u16* pbase = pbuf + (size_t)h*NTOK*NTOK;
  const u16* vbase = vt   + (size_t)h*64*NTOK;

  const int rsw = (low & 7) << 3;   // read-side XOR (row&7 == low&7 for all row tiles)

  // per-thread staging coordinates (constant across iters)
  const int srow = tid >> 4;              // rows 0..15 (+16 per s)
  const int sseg = (tid & 15) * 8;
  const int ssw  = sseg ^ ((srow & 7) << 3);

#define PV_STAGE(PD, VD, K0)                                                         \
  { _Pragma("unroll")                                                                \
    for (int s = 0; s < 4; s++){                                                     \
      int slot_ = tid + s*256;                                                       \
      int row_  = srow + s*16;                                                       \
      GLOAD_LDS16(pbase + (size_t)(m0+row_)*NTOK + (K0) + ssw, (PD) + slot_*8);      \
      GLOAD_LDS16(vbase + (size_t)row_*NTOK + (K0) + ssw,      (VD) + slot_*8);      \
    } }

#define PV_COMPUTE(PC, VC)                                                           \
  { _Pragma("unroll")                                                                \
    for (int ks = 0; ks < 128; ks += 32){                                            \
      int col_ = (ks + quad*8) ^ rsw;                                                \
      bf16x8 af_ = *(const bf16x8*)&(PC)[(wv*16 + low)*128 + col_];                  \
      bf16x8 bfr_[4];                                                                \
      _Pragma("unroll")                                                              \
      for (int nt=0; nt<4; nt++)                                                     \
        bfr_[nt] = *(const bf16x8*)&(VC)[(nt*16 + low)*128 + col_];                  \
      _Pragma("unroll")                                                              \
      for (int nt=0; nt<4; nt++)                                                     \
        acc[nt] = __builtin_amdgcn_mfma_f32_16x16x32_bf16(bfr_[nt], af_, acc[nt], 0,0,0); \
    } }

  // prologue: stage tile 0, wait
  PV_STAGE(Pl[0], Vl[0], 0)
  __syncthreads();

  #pragma unroll 2
  for (int t = 0; t < 16; ++t){
    const int cur = t & 1;
    if (t < 15) PV_STAGE(Pl[cur^1], Vl[cur^1], (t+1)*128)
    PV_COMPUTE(Pl[cur], Vl[cur])
    __syncthreads();   // drains vmcnt(0): tile t+1 ready; buf[cur] free for t+2 stage
  }
#undef PV_STAGE
#undef PV_COMPUTE

  {
    int m = m0 + wv*16 + low;
    float inv = invSbuf[(size_t)h*NTOK + m];
    #pragma unroll
    for (int nt=0; nt<4; nt++){
      int n = nt*16 + quad*4;
      u16 t0 = f2bf(acc[nt][0]*inv);
      u16 t1 = f2bf(acc[nt][1]*inv);
      u16 t2 = f2bf(acc[nt][2]*inv);
      u16 t3 = f2bf(acc[nt][3]*inv);
      uint2 o; o.x = (u32)t0 | ((u32)t1<<16); o.y = (u32)t2 | ((u32)t3<<16);
      *(uint2*)(attb + (size_t)m*DMODEL + h*64 + n) = o;
    }
  }
}

// mean_w = (1/16) sum_h p[h][n][m] * invS[h][n]. grid 2048, block 256.
__global__ __launch_bounds__(256) void k_meanw(const u16* __restrict__ pbuf,
    const float* __restrict__ invSbuf, float* __restrict__ out1)
{
  const int n = blockIdx.x, tid = threadIdx.x;
  const int m0 = tid * 8;
  float acc[8];
  #pragma unroll
  for (int i=0;i<8;i++) acc[i]=0.f;
  for (int h=0; h<NH; h++){
    float inv = invSbuf[(size_t)h*NTOK + n] * 0.0625f;
    uint4 u = *(const uint4*)(pbuf + ((size_t)h*NTOK + n)*NTOK + m0);
    float pf[8]; unpack8(u, pf);
    #pragma unroll
    for (int i=0;i<8;i++) acc[i] += pf[i]*inv;
  }
  float4 a = {acc[0],acc[1],acc[2],acc[3]};
  float4 b = {acc[4],acc[5],acc[6],acc[7]};
  float* dst = out1 + (size_t)n*NTOK + m0;
  *(float4*)dst     = a;
  *(float4*)(dst+4) = b;
}

// =====================================================================================
// SHARED kernels
// =====================================================================================

// point projections + (fast path) fused x->bf16 conversion (xb != nullptr).
__global__ __launch_bounds__(128) void k_points(const float* __restrict__ x,
    const float* __restrict__ Wpq, const float* __restrict__ bpq,
    const float* __restrict__ Wpk, const float* __restrict__ bpk,
    float* __restrict__ pqb, float* __restrict__ pkb, u16* __restrict__ xb)
{
  const int n = blockIdx.x, tid = threadIdx.x;
  __shared__ float xr[1024];
  __shared__ float dots[96];
  float4 a = *(const float4*)(x + (size_t)n*DMODEL + tid*4);
  float4 b = *(const float4*)(x + (size_t)n*DMODEL + 512 + tid*4);
  *(float4*)&xr[tid*4]       = a;
  *(float4*)&xr[512 + tid*4] = b;
  if (xb){
    uint2 o1, o2;
    o1.x = (u32)f2bf(a.x) | ((u32)f2bf(a.y)<<16);
    o1.y = (u32)f2bf(a.z) | ((u32)f2bf(a.w)<<16);
    o2.x = (u32)f2bf(b.x) | ((u32)f2bf(b.y)<<16);
    o2.y = (u32)f2bf(b.z) | ((u32)f2bf(b.w)<<16);
    *(uint2*)(xb + (size_t)n*DMODEL + tid*4)       = o1;
    *(uint2*)(xb + (size_t)n*DMODEL + 512 + tid*4) = o2;
  }
  __syncthreads();
  if (tid < 96){
    const float* W  = (tid<48) ? Wpq : Wpk;
    const float* bb = (tid<48) ? bpq : bpk;
    int c = (tid<48) ? tid : tid-48;
    float acc = 0.f;
    for (int k=0;k<DMODEL;k++) acc += xr[k]*W[(size_t)k*48 + c];
    dots[tid] = acc + bb[c];
  }
  __syncthreads();
  if (tid < 96){
    int c = (tid<48)?tid:tid-48;
    int h = c/3, cc = c - h*3;
    float* o = (tid<48)?pqb:pkb;
    o[(size_t)n*64 + h*4 + cc] = dots[tid];
  }
  if (tid < 32){
    int h = tid & 15, isk = tid >> 4;
    int b0 = isk*48 + h*3;
    float a2=dots[b0], b2=dots[b0+1], c2=dots[b0+2];
    ((isk)?pkb:pqb)[(size_t)n*64 + h*4 + 3] = a2*a2+b2*b2+c2*c2;
  }
}

__global__ __launch_bounds__(256) void k_ln(float* __restrict__ res, const float* __restrict__ gamma,
    const float* __restrict__ beta, float* __restrict__ out)
{
  const int n = blockIdx.x, tid = threadIdx.x;
  const int lane = tid & 63, w = tid >> 6;
  __shared__ float red[2][4];
  float4 v = *(const float4*)(res + (size_t)n*DMODEL + tid*4);
  float s  = v.x+v.y+v.z+v.w;
  float s2 = v.x*v.x+v.y*v.y+v.z*v.z+v.w*v.w;
  #pragma unroll
  for (int off=32; off>0; off>>=1){ s += __shfl_xor(s, off); s2 += __shfl_xor(s2, off); }
  if (lane==0){ red[0][w]=s; red[1][w]=s2; }
  __syncthreads();
  float mean = (red[0][0]+red[0][1]+red[0][2]+red[0][3]) * (1.f/1024.f);
  float m2   = (red[1][0]+red[1][1]+red[1][2]+red[1][3]) * (1.f/1024.f);
  float rs = rsqrtf(m2 - mean*mean + 1e-5f);
  float4 g = *(const float4*)(gamma + tid*4);
  float4 b = *(const float4*)(beta  + tid*4);
  float4 o;
  o.x = (v.x-mean)*rs*g.x + b.x;
  o.y = (v.y-mean)*rs*g.y + b.y;
  o.z = (v.z-mean)*rs*g.z + b.z;
  o.w = (v.w-mean)*rs*g.w + b.w;
  *(float4*)(out + (size_t)n*DMODEL + tid*4) = o;
}

// =====================================================================================
// FALLBACK PATH (fp32, small workspace)
// =====================================================================================

__global__ __launch_bounds__(256) void k_qkv_f32(const float* __restrict__ x, const float* __restrict__ W,
        const float* __restrict__ bias, float* __restrict__ qkv)
{
  const int tid = threadIdx.x;
  const int n0  = blockIdx.x * 8;
  const int c0  = blockIdx.y * 1024 + tid * 4;
  __shared__ float xs[8][1024];
  for (int i = tid; i < 2048; i += 256){
    int r = i >> 8, cc = (i & 255) << 2;
    *(float4*)&xs[r][cc] = *(const float4*)(x + (size_t)(n0 + r)*DMODEL + cc);
  }
  __syncthreads();
  float acc[8][4];
  #pragma unroll
  for (int r=0;r<8;r++){ acc[r][0]=0.f;acc[r][1]=0.f;acc[r][2]=0.f;acc[r][3]=0.f; }
  for (int k=0;k<DMODEL;k+=4){
    float4 xr[8];
    #pragma unroll
    for (int r=0;r<8;r++) xr[r] = *(const float4*)&xs[r][k];
    #pragma unroll
    for (int kk=0;kk<4;kk++){
      float4 wf = *(const float4*)(W + (size_t)(k+kk)*3072 + c0);
      #pragma unroll
      for (int r=0;r<8;r++){
        float xv = ((const float*)&xr[r])[kk];
        acc[r][0] += xv*wf.x; acc[r][1] += xv*wf.y;
        acc[r][2] += xv*wf.z; acc[r][3] += xv*wf.w;
      }
    }
  }
  float4 bb = *(const float4*)(bias + c0);
  const float sc = (blockIdx.y == 0) ? 0.125f : 1.0f;
  #pragma unroll
  for (int r=0;r<8;r++){
    float4 o;
    o.x = (acc[r][0]+bb.x)*sc; o.y = (acc[r][1]+bb.y)*sc;
    o.z = (acc[r][2]+bb.z)*sc; o.w = (acc[r][3]+bb.w)*sc;
    *(float4*)(qkv + (size_t)(n0+r)*3072 + c0) = o;
  }
}

__global__ __launch_bounds__(512) void k_out_f32(const float* __restrict__ att, const float* __restrict__ Wo,
    const float* __restrict__ bo, const float* __restrict__ x, float* __restrict__ res)
{
  const int tid = threadIdx.x;
  const int n0 = blockIdx.x * 8;
  const int c0 = tid * 2;
  __shared__ float sA[8][1024];
  for (int i = tid; i < 2048; i += 512){
    int r = i >> 8, cc = (i & 255) << 2;
    *(float4*)&sA[r][cc] = *(const float4*)(att + (size_t)(n0+r)*DMODEL + cc);
  }
  __syncthreads();
  float acc[8][2];
  #pragma unroll
  for (int r=0;r<8;r++){ acc[r][0]=0.f; acc[r][1]=0.f; }
  for (int k=0;k<DMODEL;k+=4){
    float4 ar[8];
    #pragma unroll
    for (int r=0;r<8;r++) ar[r] = *(const float4*)&sA[r][k];
    #pragma unroll
    for (int kk=0;kk<4;kk++){
      float2 wf = *(const float2*)(Wo + (size_t)(k+kk)*DMODEL + c0);
      #pragma unroll
      for (int r=0;r<8;r++){
        float av = ((const float*)&ar[r])[kk];
        acc[r][0] += av*wf.x; acc[r][1] += av*wf.y;
      }
    }
  }
  float2 bb = *(const float2*)(bo + c0);
  #pragma unroll
  for (int r=0;r<8;r++){
    float2 xf = *(const float2*)(x + (size_t)(n0+r)*DMODEL + c0);
    float2 o; o.x = acc[r][0]+bb.x+xf.x; o.y = acc[r][1]+bb.y+xf.y;
    *(float2*)(res + (size_t)(n0+r)*DMODEL + c0) = o;
  }
}

#define NT 4
__global__ __launch_bounds__(256) void k_attn_f32(const float* __restrict__ qkv,
    const float* __restrict__ pqb, const float* __restrict__ pkb,
    float* __restrict__ att, float* __restrict__ meanw)
{
  const int tid = threadIdx.x;
  const int lane = tid & 63, wvid = tid >> 6;
  const int n0 = blockIdx.x * NT;
  __shared__ __align__(16) float wrow[NT][NTOK];
  __shared__ float attp[4][NT][HD];
  __shared__ float redbuf[2][NT][4];
  float wsumr[NT][8];
  #pragma unroll
  for (int r=0;r<NT;r++){
    #pragma unroll
    for (int j=0;j<8;j++) wsumr[r][j]=0.f;
  }
  for (int h=0; h<NH; h++){
    __syncthreads();
    float lg[NT][8];
    {
      float pq0[NT],pq1[NT],pq2[NT],pq3[NT];
      #pragma unroll
      for (int r=0;r<NT;r++){
        const float* pq = pqb + (size_t)(n0+r)*64 + (h<<2);
        pq0[r]=pq[0]; pq1[r]=pq[1]; pq2[r]=pq[2]; pq3[r]=pq[3];
      }
      #pragma unroll
      for (int j=0;j<8;j++){
        int m = tid + (j<<8);
        float4 p = *(const float4*)(pkb + (size_t)m*64 + (h<<2));
        #pragma unroll
        for (int r=0;r<NT;r++)
          lg[r][j] = pq3[r] + p.w - 2.f*(pq0[r]*p.x + pq1[r]*p.y + pq2[r]*p.z);
      }
    }
    for (int c8=0;c8<8;c8++){
      float qv[NT][8];
      #pragma unroll
      for (int r=0;r<NT;r++){
        const float4* qp = (const float4*)(qkv + (size_t)(n0+r)*3072 + (h<<6) + (c8<<3));
        float4 a = qp[0], b = qp[1];
        qv[r][0]=a.x;qv[r][1]=a.y;qv[r][2]=a.z;qv[r][3]=a.w;
        qv[r][4]=b.x;qv[r][5]=b.y;qv[r][6]=b.z;qv[r][7]=b.w;
      }
      #pragma unroll
      for (int j=0;j<8;j++){
        int m = tid + (j<<8);
        const float* kp = qkv + (size_t)m*3072 + 1024 + (h<<6) + (c8<<3);
        float4 k0 = *(const float4*)kp, k1 = *(const float4*)(kp+4);
        #pragma unroll
        for (int r=0;r<NT;r++){
          lg[r][j] += qv[r][0]*k0.x+qv[r][1]*k0.y+qv[r][2]*k0.z+qv[r][3]*k0.w
                    + qv[r][4]*k1.x+qv[r][5]*k1.y+qv[r][6]*k1.z+qv[r][7]*k1.w;
        }
      }
    }
    float mx[NT];
    #pragma unroll
    for (int r=0;r<NT;r++){
      float m0 = lg[r][0];
      #pragma unroll
      for (int j=1;j<8;j++) m0 = fmaxf(m0, lg[r][j]);
      mx[r]=m0;
    }
    #pragma unroll
    for (int off=32; off>0; off>>=1){
      #pragma unroll
      for (int r=0;r<NT;r++) mx[r] = fmaxf(mx[r], __shfl_xor(mx[r], off));
    }
    if (lane==0){
      #pragma unroll
      for (int r=0;r<NT;r++) redbuf[0][r][wvid] = mx[r];
    }
    __syncthreads();
    float ps[NT];
    #pragma unroll
    for (int r=0;r<NT;r++){
      float bm = fmaxf(fmaxf(redbuf[0][r][0],redbuf[0][r][1]),
                       fmaxf(redbuf[0][r][2],redbuf[0][r][3]));
      float s = 0.f;
      #pragma unroll
      for (int j=0;j<8;j++){ float p = __expf(lg[r][j]-bm); lg[r][j]=p; s+=p; }
      ps[r]=s;
    }
    #pragma unroll
    for (int off=32; off>0; off>>=1){
      #pragma unroll
      for (int r=0;r<NT;r++) ps[r] += __shfl_xor(ps[r], off);
    }
    if (lane==0){
      #pragma unroll
      for (int r=0;r<NT;r++) redbuf[1][r][wvid] = ps[r];
    }
    __syncthreads();
    #pragma unroll
    for (int r=0;r<NT;r++){
      float s = redbuf[1][r][0]+redbuf[1][r][1]+redbuf[1][r][2]+redbuf[1][r][3];
      float inv = 1.0f / s;
      #pragma unroll
      for (int j=0;j<8;j++){
        float w = lg[r][j]*inv;
        wsumr[r][j] += w;
        wrow[r][tid + (j<<8)] = w;
      }
    }
    __syncthreads();
    {
      const int c = wvid, d = lane;
      float part[NT];
      #pragma unroll
      for (int r=0;r<NT;r++) part[r]=0.f;
      const size_t vofs = 2048 + (h<<6) + d;
      for (int mm = c<<9; mm < ((c+1)<<9); mm += 4){
        float wf[NT][4];
        #pragma unroll
        for (int r=0;r<NT;r++)
          *(float4*)wf[r] = *(const float4*)&wrow[r][mm];
        #pragma unroll
        for (int e=0;e<4;e++){
          float vvv = qkv[(size_t)(mm+e)*3072 + vofs];
          #pragma unroll
          for (int r=0;r<NT;r++) part[r] += wf[r][e]*vvv;
        }
      }
      #pragma unroll
      for (int r=0;r<NT;r++) attp[c][r][d] = part[r];
    }
    __syncthreads();
    {
      const int r = wvid, d = lane;
      float s = attp[0][r][d]+attp[1][r][d]+attp[2][r][d]+attp[3][r][d];
      att[(size_t)(n0+r)*DMODEL + (h<<6) + d] = s;
    }
  }
  #pragma unroll
  for (int r=0;r<NT;r++){
    #pragma unroll
    for (int j=0;j<8;j++)
      meanw[(size_t)(n0+r)*NTOK + tid + (j<<8)] = wsumr[r][j]*0.0625f;
  }
}

// =====================================================================================
extern "C" void kernel_launch(void* const* d_in, const int* in_sizes, int n_in,
                              void* d_out, int out_size, void* d_ws, size_t ws_size,
                              hipStream_t stream)
{
  const float* x     = (const float*)d_in[0];
  const float* Wqkv  = (const float*)d_in[3];
  const float* bqkv  = (const float*)d_in[4];
  const float* Wpq   = (const float*)d_in[5];
  const float* bpq   = (const float*)d_in[6];
  const float* Wpk   = (const float*)d_in[7];
  const float* bpk   = (const float*)d_in[8];
  const float* Wo    = (const float*)d_in[9];
  const float* bo    = (const float*)d_in[10];
  const float* gamma = (const float*)d_in[11];
  const float* beta  = (const float*)d_in[12];

  float* out0 = (float*)d_out;                   // ln      [2048,1024] f32
  float* out1 = out0 + (size_t)NTOK*DMODEL;      // mean_w  [2048,2048] f32

  const size_t sz_qkvb = (size_t)NTOK*3072*2;          // 12.6 MB
  const size_t sz_vt   = (size_t)NH*HD*NTOK*2;         //  4.2 MB
  const size_t sz_pq   = (size_t)NTOK*64*4;            //  0.5 MB
  const size_t sz_attb = (size_t)NTOK*DMODEL*2;        //  4.2 MB
  const size_t sz_wot  = (size_t)DMODEL*DMODEL*2;      //  2.1 MB
  const size_t sz_pbuf = (size_t)NH*NTOK*NTOK*2;       // 134.2 MB
  const size_t sz_invS = (size_t)NH*NTOK*4;            //  0.13 MB
  const size_t need_fast = sz_qkvb + sz_vt + 2*sz_pq + sz_attb + sz_wot + sz_pbuf + sz_invS;

  char* ws = (char*)d_ws;
  if (ws_size >= need_fast){
    u16*   qkvb = (u16*)ws;    ws += sz_qkvb;
    u16*   vt   = (u16*)ws;    ws += sz_vt;
    float* pqb  = (float*)ws;  ws += sz_pq;
    float* pkb  = (float*)ws;  ws += sz_pq;
    u16*   attb = (u16*)ws;    ws += sz_attb;
    u16*   Wot  = (u16*)ws;    ws += sz_wot;
    u16*   pbuf = (u16*)ws;    ws += sz_pbuf;
    float* invS = (float*)ws;  ws += sz_invS;
    // xb and Wt alias the (dead-until-attention) pbuf region
    u16*   xb   = pbuf;                                        // 4.2 MB
    u16*   Wt   = pbuf + (size_t)NTOK*DMODEL;                  // 6.3 MB

    k_points  <<<NTOK,          128, 0, stream>>>(x, Wpq, bpq, Wpk, bpk, pqb, pkb, xb);
    k_tcvt    <<<dim3(48,16),   256, 0, stream>>>(Wqkv, Wt, DMODEL, 3*DMODEL);
    k_tcvt    <<<dim3(16,16),   256, 0, stream>>>(Wo, Wot, DMODEL, DMODEL);
    k_gemm    <<<dim3(24,32),   256, 0, stream>>>(xb, Wt, bqkv, nullptr, qkvb, nullptr,
                                                  NTOK, 3*DMODEL, DMODEL, 1);
    k_vt      <<<dim3(32,16),   256, 0, stream>>>(qkvb, vt);
    k_attn_qk <<<dim3(64,16),   512, 0, stream>>>(qkvb, pqb, pkb, pbuf, invS);
    k_pv      <<<512,           256, 0, stream>>>(pbuf, vt, invS, attb);
    k_meanw   <<<NTOK,          256, 0, stream>>>(pbuf, invS, out1);
    k_gemm    <<<dim3(8,32),    256, 0, stream>>>(attb, Wot, bo, x, nullptr, out0,
                                                  NTOK, DMODEL, DMODEL, 0);
    k_ln      <<<NTOK,          256, 0, stream>>>(out0, gamma, beta, out0);
  } else {
    float* qkv = (float*)ws; ws += (size_t)NTOK*3072*4;
    float* pqb = (float*)ws; ws += sz_pq;
    float* pkb = (float*)ws; ws += sz_pq;
    float* att = (float*)ws; ws += (size_t)NTOK*DMODEL*4;

    k_qkv_f32 <<<dim3(256,3), 256, 0, stream>>>(x, Wqkv, bqkv, qkv);
    k_points  <<<NTOK,        128, 0, stream>>>(x, Wpq, bpq, Wpk, bpk, pqb, pkb, nullptr);
    k_attn_f32<<<NTOK/NT,     256, 0, stream>>>(qkv, pqb, pkb, att, out1);
    k_out_f32 <<<256,         512, 0, stream>>>(att, Wo, bo, x, out0);
    k_ln      <<<NTOK,        256, 0, stream>>>(out0, gamma, beta, out0);
  }
}

// Round 16
// 299.633 us; speedup vs baseline: 1.0649x; 1.0057x over previous
//
#include <hip/hip_runtime.h>

typedef unsigned short u16;
typedef unsigned int   u32;
typedef short bf16x8 __attribute__((ext_vector_type(8)));
typedef float f32x4  __attribute__((ext_vector_type(4)));
typedef unsigned int u32x4 __attribute__((ext_vector_type(4)));

#define NTOK   2048
#define DMODEL 1024
#define NH     16
#define HD     64

__device__ __forceinline__ u16 f2bf(float f){
  u32 x = __float_as_uint(f);
  return (u16)((x + 0x7fffu + ((x>>16)&1u)) >> 16);   // RNE
}
__device__ __forceinline__ void unpack8(uint4 u, float* f){
  f[0]=__uint_as_float(u.x<<16); f[1]=__uint_as_float(u.x&0xffff0000u);
  f[2]=__uint_as_float(u.y<<16); f[3]=__uint_as_float(u.y&0xffff0000u);
  f[4]=__uint_as_float(u.z<<16); f[5]=__uint_as_float(u.z&0xffff0000u);
  f[6]=__uint_as_float(u.w<<16); f[7]=__uint_as_float(u.w&0xffff0000u);
}
// pack 2 f32 -> 2 bf16 (RNE) in one VALU inst. lo = bf16(a), hi = bf16(b).
__device__ __forceinline__ u32 pk_bf16(float a, float b){
  u32 r;
  asm("v_cvt_pk_bf16_f32 %0, %1, %2" : "=v"(r) : "v"(a), "v"(b));
  return r;
}

// async global->LDS, 16B per lane. LDS dest must be wave-uniform base + lane*16 (linear).
#define GLOAD_LDS16(GP, LP) \
  __builtin_amdgcn_global_load_lds((__attribute__((address_space(1))) const void*)(GP), \
                                   (__attribute__((address_space(3))) void*)(LP), 16, 0, 0)

// =====================================================================================
// FAST PATH
// =====================================================================================

// W [K][N] fp32 -> Wt [N][K] bf16 (transpose + cvt). grid (N/64, K/64), block 256.
__global__ __launch_bounds__(256) void k_tcvt(const float* __restrict__ W, u16* __restrict__ Wt,
                                              int K, int N)
{
  const int tid = threadIdx.x;
  const int n0 = blockIdx.x * 64, k0 = blockIdx.y * 64;
  __shared__ float tileF[64*68];
  {
    int kk = tid >> 2, nseg = (tid & 3) * 16;
    const float* src = W + (size_t)(k0 + kk)*N + n0 + nseg;
    #pragma unroll
    for (int i=0;i<4;i++)
      *(float4*)&tileF[kk*68 + nseg + i*4] = *(const float4*)(src + i*4);
  }
  __syncthreads();
  {
    int n = tid >> 2, kseg = (tid & 3) * 16;
    u16 tmp[16];
    #pragma unroll
    for (int j=0;j<16;j++) tmp[j] = f2bf(tileF[(kseg + j)*68 + n]);
    uint4 o0, o1;
    o0.x=(u32)tmp[0]|((u32)tmp[1]<<16);  o0.y=(u32)tmp[2]|((u32)tmp[3]<<16);
    o0.z=(u32)tmp[4]|((u32)tmp[5]<<16);  o0.w=(u32)tmp[6]|((u32)tmp[7]<<16);
    o1.x=(u32)tmp[8]|((u32)tmp[9]<<16);  o1.y=(u32)tmp[10]|((u32)tmp[11]<<16);
    o1.z=(u32)tmp[12]|((u32)tmp[13]<<16);o1.w=(u32)tmp[14]|((u32)tmp[15]<<16);
    u16* dst = Wt + (size_t)(n0 + n)*K + k0 + kseg;
    *(uint4*)dst       = o0;
    *(uint4*)(dst + 8) = o1;
  }
}

// Generic bf16 MFMA GEMM: out[M][N] = A[M][K] @ Bt[N][K]^T + bias.
// M-tile 64, N-tile 128. global_load_lds width-16 staging, linear LDS tiles.
// 1-D grid with XCD-PINNED A-row mapping: bid = (y&7) + 8*(x + NX*(y>>3)) so all
// NX blocks of a y-row (sharing the 128KB A-panel) land on XCD y&7 -> A L2-resident
// instead of re-fetched per XCD from L3. Bijective for NY multiple of 8.
// qkvmode=1: out bf16, cols<1024 scaled by 1/8.  qkvmode=0: out fp32 = acc+bias+resid.
// grid NX*NY blocks (NX=N/128, NY=M/64), block 256 (4 waves, 2x2).
__global__ __launch_bounds__(256) void k_gemm(
    const u16* __restrict__ A, const u16* __restrict__ Bt,
    const float* __restrict__ bias, const float* __restrict__ resid,
    u16* __restrict__ outb, float* __restrict__ outf,
    int M, int N, int K, int qkvmode)
{
  const int tid  = threadIdx.x;
  const int lane = tid & 63, wv = tid >> 6;
  const int quad = lane >> 4, low = lane & 15;
  const int wm = wv >> 1, wn = wv & 1;
  // XCD-pinned decode: xcd = bid&7 == y&7
  const int NX   = N >> 7;
  const int xcd  = blockIdx.x & 7;
  const int t_   = blockIdx.x >> 3;
  const int bx   = t_ % NX;
  const int by   = ((t_ / NX) << 3) + xcd;
  const int m0 = by * 64, n0 = bx * 128;

  __shared__ u16 Al[64*64];
  __shared__ u16 Bl[128*64];

  const f32x4 zz = {0.f,0.f,0.f,0.f};
  f32x4 acc[2][4];
  #pragma unroll
  for (int mt=0;mt<2;mt++)
    #pragma unroll
    for (int nt=0;nt<4;nt++) acc[mt][nt] = zz;

  for (int k0 = 0; k0 < K; k0 += 64){
    #pragma unroll
    for (int s = 0; s < 2; s++){
      int slot = tid + s*256;
      int row = slot >> 3, seg = (slot & 7) * 8;
      GLOAD_LDS16(A + (size_t)(m0+row)*K + k0 + seg, &Al[slot*8]);
    }
    #pragma unroll
    for (int s = 0; s < 4; s++){
      int slot = tid + s*256;
      int row = slot >> 3, seg = (slot & 7) * 8;
      GLOAD_LDS16(Bt + (size_t)(n0+row)*K + k0 + seg, &Bl[slot*8]);
    }
    __syncthreads();
    #pragma unroll
    for (int ks = 0; ks < 64; ks += 32){
      bf16x8 af[2], bfr[4];
      #pragma unroll
      for (int mt=0; mt<2; mt++)
        af[mt] = *(const bf16x8*)&Al[(wm*32 + mt*16 + low)*64 + ks + quad*8];
      #pragma unroll
      for (int nt=0; nt<4; nt++)
        bfr[nt] = *(const bf16x8*)&Bl[(wn*64 + nt*16 + low)*64 + ks + quad*8];
      #pragma unroll
      for (int mt=0; mt<2; mt++)
        #pragma unroll
        for (int nt=0; nt<4; nt++)
          // swapped operands: D row(quad*4+rg)=n, col(low)=m -> vectorized n-stores
          acc[mt][nt] = __builtin_amdgcn_mfma_f32_16x16x32_bf16(bfr[nt], af[mt], acc[mt][nt], 0,0,0);
    }
    __syncthreads();
  }

  #pragma unroll
  for (int mt=0; mt<2; mt++){
    int m = m0 + wm*32 + mt*16 + low;
    #pragma unroll
    for (int nt=0; nt<4; nt++){
      int n = n0 + wn*64 + nt*16 + quad*4;
      float4 bb = *(const float4*)(bias + n);
      float v0 = acc[mt][nt][0] + bb.x;
      float v1 = acc[mt][nt][1] + bb.y;
      float v2 = acc[mt][nt][2] + bb.z;
      float v3 = acc[mt][nt][3] + bb.w;
      if (qkvmode){
        float sc = (n < 1024) ? 0.125f : 1.0f;
        v0*=sc; v1*=sc; v2*=sc; v3*=sc;
        uint2 pk;
        pk.x = (u32)f2bf(v0) | ((u32)f2bf(v1)<<16);
        pk.y = (u32)f2bf(v2) | ((u32)f2bf(v3)<<16);
        *(uint2*)(outb + (size_t)m*N + n) = pk;
      } else {
        float4 xr = *(const float4*)(resid + (size_t)m*N + n);
        float4 o = {v0+xr.x, v1+xr.y, v2+xr.z, v3+xr.w};
        *(float4*)(outf + (size_t)m*N + n) = o;
      }
    }
  }
}

// transpose v: vt[h][d][m] bf16. grid (32 mtiles, 16 h), block 256.
__global__ __launch_bounds__(256) void k_vt(const u16* __restrict__ qkvb, u16* __restrict__ vt)
{
  const int m0 = blockIdx.x * 64;
  const int h  = blockIdx.y;
  const int tid = threadIdx.x;
  __shared__ u16 tile[64][72];
  {
    int row = tid >> 2, seg = (tid & 3) * 8;
    const u16* src = qkvb + (size_t)(m0 + row)*3072 + 2048 + h*64;
    *(uint4*)&tile[row][seg]      = *(const uint4*)(src + seg);
    *(uint4*)&tile[row][32 + seg] = *(const uint4*)(src + 32 + seg);
  }
  __syncthreads();
  {
    int d = tid >> 2, mseg = (tid & 3) * 16;
    __align__(16) u16 tmp[16];
    #pragma unroll
    for (int j=0;j<16;j++) tmp[j] = tile[mseg + j][d];
    u16* dst = vt + (size_t)(h*64 + d)*2048 + m0 + mseg;
    *(uint4*)dst       = *(uint4*)&tmp[0];
    *(uint4*)(dst + 8) = *(uint4*)&tmp[8];
  }
}

// QK + softmax-numerator kernel. grid (64 ntiles of 32 rows, 16 heads), block 512
// (8 waves; each wave owns a 256-key segment = 8 steps of 32 keys).
// UNCAPPED launch_bounds: the old (512,4) pinned VGPR at 64, which forbade the
// compiler from hoisting next-step K/pk loads across the MFMA/exp block (all step
// addresses are loop-invariant-independent). Natural alloc ~80-96 -> 3 blocks/CU
// (24 waves, > measured-effective 12) + compiler software pipelining.
// Key-permuted loads; 16B uint4 stores; cvt_pk packing; p = exp(l-48).
__global__ __launch_bounds__(512) void k_attn_qk(
    const u16* __restrict__ qkvb,
    const float* __restrict__ pqb, const float* __restrict__ pkb,
    u16* __restrict__ pbuf, float* __restrict__ invSbuf)
{
  const int tid  = threadIdx.x;
  const int lane = tid & 63, wv = tid >> 6;
  const int quad = lane >> 4, low = lane & 15;
  const int n0 = blockIdx.x * 32;
  const int h  = blockIdx.y;

  __shared__ float rs[8][32];

  bf16x8 qf[2][2];
  #pragma unroll
  for (int rt=0; rt<2; rt++)
    #pragma unroll
    for (int df=0; df<2; df++)
      qf[rt][df] = *(const bf16x8*)(qkvb + (size_t)(n0 + rt*16 + low)*3072 + h*64 + df*32 + quad*8);

  // pq for this lane's own q-rows (rt*16+low)
  float4 pqr[2];
  #pragma unroll
  for (int rt=0; rt<2; rt++)
    pqr[rt] = *(const float4*)(pqb + (size_t)(n0 + rt*16 + low)*64 + h*4);

  const f32x4 zz = {0.f,0.f,0.f,0.f};
  float psum[2] = {0.f, 0.f};

  const int kperm = ((low>>2)<<3) + (low&3);   // + kt*4 per kt

  for (int step=0; step<8; step++){
    const int ks = (wv<<8) + (step<<5);
    u32x4 st0, st1;
    #pragma unroll
    for (int kt=0; kt<2; kt++){
      const u16* kbase = qkvb + (size_t)(ks + kperm + kt*4)*3072 + 1024 + h*64 + quad*8;
      bf16x8 kf0 = *(const bf16x8*)(kbase);
      bf16x8 kf1 = *(const bf16x8*)(kbase + 32);
      // swapped: D-row = key-slot (quad*4+rg) -> key ks + quad*8 + kt*4 + rg
      f32x4 a0 = zz, a1 = zz;
      a0 = __builtin_amdgcn_mfma_f32_16x16x32_bf16(kf0, qf[0][0], a0, 0,0,0);
      a0 = __builtin_amdgcn_mfma_f32_16x16x32_bf16(kf1, qf[0][1], a0, 0,0,0);
      a1 = __builtin_amdgcn_mfma_f32_16x16x32_bf16(kf0, qf[1][0], a1, 0,0,0);
      a1 = __builtin_amdgcn_mfma_f32_16x16x32_bf16(kf1, qf[1][1], a1, 0,0,0);
      float pv0[4], pv1[4];
      float s0 = 0.f, s1 = 0.f;
      #pragma unroll
      for (int rg=0; rg<4; rg++){
        float4 pk = *(const float4*)(pkb + (size_t)(ks + quad*8 + kt*4 + rg)*64 + h*4);
        float pkc = pk.w - 48.f;
        float4 pq0 = pqr[0], pq1 = pqr[1];
        float b0 = pq0.w + pkc - 2.f*(pq0.x*pk.x + pq0.y*pk.y + pq0.z*pk.z);
        float b1 = pq1.w + pkc - 2.f*(pq1.x*pk.x + pq1.y*pk.y + pq1.z*pk.z);
        pv0[rg] = __expf(a0[rg] + b0);
        pv1[rg] = __expf(a1[rg] + b1);
        s0 += pv0[rg]; s1 += pv1[rg];
      }
      psum[0] += s0; psum[1] += s1;
      u32 wa = pk_bf16(pv0[0], pv0[1]);
      u32 wb = pk_bf16(pv0[2], pv0[3]);
      u32 wc = pk_bf16(pv1[0], pv1[1]);
      u32 wd = pk_bf16(pv1[2], pv1[3]);
      if (kt == 0){ st0.x = wa; st0.y = wb; st1.x = wc; st1.y = wd; }
      else        { st0.z = wa; st0.w = wb; st1.z = wc; st1.w = wd; }
    }
    // row (n0+low) keys [ks+quad*8, ks+quad*8+8) -- 16B store, 4 quads cover 64B
    *(u32x4*)(pbuf + ((size_t)h*NTOK + n0 + low)*NTOK      + ks + quad*8) = st0;
    *(u32x4*)(pbuf + ((size_t)h*NTOK + n0 + 16 + low)*NTOK + ks + quad*8) = st1;
  }

  // psum: lane-local over its keys; reduce across quads (lane bits 4,5)
  #pragma unroll
  for (int rt=0; rt<2; rt++){
    psum[rt] += __shfl_xor(psum[rt], 16);
    psum[rt] += __shfl_xor(psum[rt], 32);
  }
  if (quad == 0){
    rs[wv][low]      = psum[0];
    rs[wv][16 + low] = psum[1];
  }
  __syncthreads();
  if (tid < 32){
    float s = rs[0][tid] + rs[1][tid] + rs[2][tid] + rs[3][tid]
            + rs[4][tid] + rs[5][tid] + rs[6][tid] + rs[7][tid];
    invSbuf[(size_t)h*NTOK + n0 + tid] = 1.0f / s;
  }
}

// PV as a per-head GEMM: attb[m][h*64+n] = invS[h][m] * sum_k p[h][m][k] * vt[h][n][k].
// ROUND-11 VERSION (measured 59us). M-tile 64, BK=128, 1-D grid 512 (XCD-pinned:
// head h on XCD h&7), block 256 (4 waves), 2-phase double-buffer, XOR-swizzle
// both-sides (rule #21).
__global__ __launch_bounds__(256) void k_pv(
    const u16* __restrict__ pbuf, const u16* __restrict__ vt,
    const float* __restrict__ invSbuf, u16* __restrict__ attb)
{
  const int tid  = threadIdx.x;
  const int lane = tid & 63, wv = tid >> 6;
  const int quad = lane >> 4, low = lane & 15;
  // bid -> (head, m-tile): xcd = bid&7 hosts heads {xcd, xcd+8}; bijective.
  const int bid  = blockIdx.x;
  const int xcd  = bid & 7;
  const int slot = bid >> 3;                 // 0..63
  const int h    = xcd + ((slot >> 5) << 3); // slot<32 -> xcd, else xcd+8
  const int m0   = (slot & 31) * 64;

  __shared__ u16 Pl[2][64*128];
  __shared__ u16 Vl[2][64*128];

  const f32x4 zz = {0.f,0.f,0.f,0.f};
  f32x4 acc[4];
  #pragma unroll
  for (int nt=0;nt<4;nt++) acc[nt] = zz;

  const u16* pbase = pbuf + (size_t)h*NTOK*NTOK;
  const u16* vbase = vt   + (size_t)h*64*NTOK;

  const int rsw = (low & 7) << 3;   // read-side XOR (row&7 == low&7 for all row tiles)

  // per-thread staging coordinates (constant across iters)
  const int srow = tid >> 4;              // rows 0..15 (+16 per s)
  const int sseg = (tid & 15) * 8;
  const int ssw  = sseg ^ ((srow & 7) << 3);

#define PV_STAGE(PD, VD, K0)                                                         \
  { _Pragma("unroll")                                                                \
    for (int s = 0; s < 4; s++){                                                     \
      int slot_ = tid + s*256;                                                       \
      int row_  = srow + s*16;                                                       \
      GLOAD_LDS16(pbase + (size_t)(m0+row_)*NTOK + (K0) + ssw, (PD) + slot_*8);      \
      GLOAD_LDS16(vbase + (size_t)row_*NTOK + (K0) + ssw,      (VD) + slot_*8);      \
    } }

#define PV_COMPUTE(PC, VC)                                                           \
  { _Pragma("unroll")                                                                \
    for (int ks = 0; ks < 128; ks += 32){                                            \
      int col_ = (ks + quad*8) ^ rsw;                                                \
      bf16x8 af_ = *(const bf16x8*)&(PC)[(wv*16 + low)*128 + col_];                  \
      bf16x8 bfr_[4];                                                                \
      _Pragma("unroll")                                                              \
      for (int nt=0; nt<4; nt++)                                                     \
        bfr_[nt] = *(const bf16x8*)&(VC)[(nt*16 + low)*128 + col_];                  \
      _Pragma("unroll")                                                              \
      for (int nt=0; nt<4; nt++)                                                     \
        acc[nt] = __builtin_amdgcn_mfma_f32_16x16x32_bf16(bfr_[nt], af_, acc[nt], 0,0,0); \
    } }

  // prologue: stage tile 0, wait
  PV_STAGE(Pl[0], Vl[0], 0)
  __syncthreads();

  #pragma unroll 2
  for (int t = 0; t < 16; ++t){
    const int cur = t & 1;
    if (t < 15) PV_STAGE(Pl[cur^1], Vl[cur^1], (t+1)*128)
    PV_COMPUTE(Pl[cur], Vl[cur])
    __syncthreads();   // drains vmcnt(0): tile t+1 ready; buf[cur] free for t+2 stage
  }
#undef PV_STAGE
#undef PV_COMPUTE

  {
    int m = m0 + wv*16 + low;
    float inv = invSbuf[(size_t)h*NTOK + m];
    #pragma unroll
    for (int nt=0; nt<4; nt++){
      int n = nt*16 + quad*4;
      u16 t0 = f2bf(acc[nt][0]*inv);
      u16 t1 = f2bf(acc[nt][1]*inv);
      u16 t2 = f2bf(acc[nt][2]*inv);
      u16 t3 = f2bf(acc[nt][3]*inv);
      uint2 o; o.x = (u32)t0 | ((u32)t1<<16); o.y = (u32)t2 | ((u32)t3<<16);
      *(uint2*)(attb + (size_t)m*DMODEL + h*64 + n) = o;
    }
  }
}

// mean_w = (1/16) sum_h p[h][n][m] * invS[h][n]. grid 2048, block 256.
__global__ __launch_bounds__(256) void k_meanw(const u16* __restrict__ pbuf,
    const float* __restrict__ invSbuf, float* __restrict__ out1)
{
  const int n = blockIdx.x, tid = threadIdx.x;
  const int m0 = tid * 8;
  float acc[8];
  #pragma unroll
  for (int i=0;i<8;i++) acc[i]=0.f;
  for (int h=0; h<NH; h++){
    float inv = invSbuf[(size_t)h*NTOK + n] * 0.0625f;
    uint4 u = *(const uint4*)(pbuf + ((size_t)h*NTOK + n)*NTOK + m0);
    float pf[8]; unpack8(u, pf);
    #pragma unroll
    for (int i=0;i<8;i++) acc[i] += pf[i]*inv;
  }
  float4 a = {acc[0],acc[1],acc[2],acc[3]};
  float4 b = {acc[4],acc[5],acc[6],acc[7]};
  float* dst = out1 + (size_t)n*NTOK + m0;
  *(float4*)dst     = a;
  *(float4*)(dst+4) = b;
}

// =====================================================================================
// SHARED kernels
// =====================================================================================

// point projections + (fast path) fused x->bf16 conversion (xb != nullptr).
__global__ __launch_bounds__(128) void k_points(const float* __restrict__ x,
    const float* __restrict__ Wpq, const float* __restrict__ bpq,
    const float* __restrict__ Wpk, const float* __restrict__ bpk,
    float* __restrict__ pqb, float* __restrict__ pkb, u16* __restrict__ xb)
{
  const int n = blockIdx.x, tid = threadIdx.x;
  __shared__ float xr[1024];
  __shared__ float dots[96];
  float4 a = *(const float4*)(x + (size_t)n*DMODEL + tid*4);
  float4 b = *(const float4*)(x + (size_t)n*DMODEL + 512 + tid*4);
  *(float4*)&xr[tid*4]       = a;
  *(float4*)&xr[512 + tid*4] = b;
  if (xb){
    uint2 o1, o2;
    o1.x = (u32)f2bf(a.x) | ((u32)f2bf(a.y)<<16);
    o1.y = (u32)f2bf(a.z) | ((u32)f2bf(a.w)<<16);
    o2.x = (u32)f2bf(b.x) | ((u32)f2bf(b.y)<<16);
    o2.y = (u32)f2bf(b.z) | ((u32)f2bf(b.w)<<16);
    *(uint2*)(xb + (size_t)n*DMODEL + tid*4)       = o1;
    *(uint2*)(xb + (size_t)n*DMODEL + 512 + tid*4) = o2;
  }
  __syncthreads();
  if (tid < 96){
    const float* W  = (tid<48) ? Wpq : Wpk;
    const float* bb = (tid<48) ? bpq : bpk;
    int c = (tid<48) ? tid : tid-48;
    float acc = 0.f;
    for (int k=0;k<DMODEL;k++) acc += xr[k]*W[(size_t)k*48 + c];
    dots[tid] = acc + bb[c];
  }
  __syncthreads();
  if (tid < 96){
    int c = (tid<48)?tid:tid-48;
    int h = c/3, cc = c - h*3;
    float* o = (tid<48)?pqb:pkb;
    o[(size_t)n*64 + h*4 + cc] = dots[tid];
  }
  if (tid < 32){
    int h = tid & 15, isk = tid >> 4;
    int b0 = isk*48 + h*3;
    float a2=dots[b0], b2=dots[b0+1], c2=dots[b0+2];
    ((isk)?pkb:pqb)[(size_t)n*64 + h*4 + 3] = a2*a2+b2*b2+c2*c2;
  }
}

__global__ __launch_bounds__(256) void k_ln(float* __restrict__ res, const float* __restrict__ gamma,
    const float* __restrict__ beta, float* __restrict__ out)
{
  const int n = blockIdx.x, tid = threadIdx.x;
  const int lane = tid & 63, w = tid >> 6;
  __shared__ float red[2][4];
  float4 v = *(const float4*)(res + (size_t)n*DMODEL + tid*4);
  float s  = v.x+v.y+v.z+v.w;
  float s2 = v.x*v.x+v.y*v.y+v.z*v.z+v.w*v.w;
  #pragma unroll
  for (int off=32; off>0; off>>=1){ s += __shfl_xor(s, off); s2 += __shfl_xor(s2, off); }
  if (lane==0){ red[0][w]=s; red[1][w]=s2; }
  __syncthreads();
  float mean = (red[0][0]+red[0][1]+red[0][2]+red[0][3]) * (1.f/1024.f);
  float m2   = (red[1][0]+red[1][1]+red[1][2]+red[1][3]) * (1.f/1024.f);
  float rs = rsqrtf(m2 - mean*mean + 1e-5f);
  float4 g = *(const float4*)(gamma + tid*4);
  float4 b = *(const float4*)(beta  + tid*4);
  float4 o;
  o.x = (v.x-mean)*rs*g.x + b.x;
  o.y = (v.y-mean)*rs*g.y + b.y;
  o.z = (v.z-mean)*rs*g.z + b.z;
  o.w = (v.w-mean)*rs*g.w + b.w;
  *(float4*)(out + (size_t)n*DMODEL + tid*4) = o;
}

// =====================================================================================
// FALLBACK PATH (fp32, small workspace)
// =====================================================================================

__global__ __launch_bounds__(256) void k_qkv_f32(const float* __restrict__ x, const float* __restrict__ W,
        const float* __restrict__ bias, float* __restrict__ qkv)
{
  const int tid = threadIdx.x;
  const int n0  = blockIdx.x * 8;
  const int c0  = blockIdx.y * 1024 + tid * 4;
  __shared__ float xs[8][1024];
  for (int i = tid; i < 2048; i += 256){
    int r = i >> 8, cc = (i & 255) << 2;
    *(float4*)&xs[r][cc] = *(const float4*)(x + (size_t)(n0 + r)*DMODEL + cc);
  }
  __syncthreads();
  float acc[8][4];
  #pragma unroll
  for (int r=0;r<8;r++){ acc[r][0]=0.f;acc[r][1]=0.f;acc[r][2]=0.f;acc[r][3]=0.f; }
  for (int k=0;k<DMODEL;k+=4){
    float4 xr[8];
    #pragma unroll
    for (int r=0;r<8;r++) xr[r] = *(const float4*)&xs[r][k];
    #pragma unroll
    for (int kk=0;kk<4;kk++){
      float4 wf = *(const float4*)(W + (size_t)(k+kk)*3072 + c0);
      #pragma unroll
      for (int r=0;r<8;r++){
        float xv = ((const float*)&xr[r])[kk];
        acc[r][0] += xv*wf.x; acc[r][1] += xv*wf.y;
        acc[r][2] += xv*wf.z; acc[r][3] += xv*wf.w;
      }
    }
  }
  float4 bb = *(const float4*)(bias + c0);
  const float sc = (blockIdx.y == 0) ? 0.125f : 1.0f;
  #pragma unroll
  for (int r=0;r<8;r++){
    float4 o;
    o.x = (acc[r][0]+bb.x)*sc; o.y = (acc[r][1]+bb.y)*sc;
    o.z = (acc[r][2]+bb.z)*sc; o.w = (acc[r][3]+bb.w)*sc;
    *(float4*)(qkv + (size_t)(n0+r)*3072 + c0) = o;
  }
}

__global__ __launch_bounds__(512) void k_out_f32(const float* __restrict__ att, const float* __restrict__ Wo,
    const float* __restrict__ bo, const float* __restrict__ x, float* __restrict__ res)
{
  const int tid = threadIdx.x;
  const int n0 = blockIdx.x * 8;
  const int c0 = tid * 2;
  __shared__ float sA[8][1024];
  for (int i = tid; i < 2048; i += 512){
    int r = i >> 8, cc = (i & 255) << 2;
    *(float4*)&sA[r][cc] = *(const float4*)(att + (size_t)(n0+r)*DMODEL + cc);
  }
  __syncthreads();
  float acc[8][2];
  #pragma unroll
  for (int r=0;r<8;r++){ acc[r][0]=0.f; acc[r][1]=0.f; }
  for (int k=0;k<DMODEL;k+=4){
    float4 ar[8];
    #pragma unroll
    for (int r=0;r<8;r++) ar[r] = *(const float4*)&sA[r][k];
    #pragma unroll
    for (int kk=0;kk<4;kk++){
      float2 wf = *(const float2*)(Wo + (size_t)(k+kk)*DMODEL + c0);
      #pragma unroll
      for (int r=0;r<8;r++){
        float av = ((const float*)&ar[r])[kk];
        acc[r][0] += av*wf.x; acc[r][1] += av*wf.y;
      }
    }
  }
  float2 bb = *(const float2*)(bo + c0);
  #pragma unroll
  for (int r=0;r<8;r++){
    float2 xf = *(const float2*)(x + (size_t)(n0+r)*DMODEL + c0);
    float2 o; o.x = acc[r][0]+bb.x+xf.x; o.y = acc[r][1]+bb.y+xf.y;
    *(float2*)(res + (size_t)(n0+r)*DMODEL + c0) = o;
  }
}

#define NT 4
__global__ __launch_bounds__(256) void k_attn_f32(const float* __restrict__ qkv,
    const float* __restrict__ pqb, const float* __restrict__ pkb,
    float* __restrict__ att, float* __restrict__ meanw)
{
  const int tid = threadIdx.x;
  const int lane = tid & 63, wvid = tid >> 6;
  const int n0 = blockIdx.x * NT;
  __shared__ __align__(16) float wrow[NT][NTOK];
  __shared__ float attp[4][NT][HD];
  __shared__ float redbuf[2][NT][4];
  float wsumr[NT][8];
  #pragma unroll
  for (int r=0;r<NT;r++){
    #pragma unroll
    for (int j=0;j<8;j++) wsumr[r][j]=0.f;
  }
  for (int h=0; h<NH; h++){
    __syncthreads();
    float lg[NT][8];
    {
      float pq0[NT],pq1[NT],pq2[NT],pq3[NT];
      #pragma unroll
      for (int r=0;r<NT;r++){
        const float* pq = pqb + (size_t)(n0+r)*64 + (h<<2);
        pq0[r]=pq[0]; pq1[r]=pq[1]; pq2[r]=pq[2]; pq3[r]=pq[3];
      }
      #pragma unroll
      for (int j=0;j<8;j++){
        int m = tid + (j<<8);
        float4 p = *(const float4*)(pkb + (size_t)m*64 + (h<<2));
        #pragma unroll
        for (int r=0;r<NT;r++)
          lg[r][j] = pq3[r] + p.w - 2.f*(pq0[r]*p.x + pq1[r]*p.y + pq2[r]*p.z);
      }
    }
    for (int c8=0;c8<8;c8++){
      float qv[NT][8];
      #pragma unroll
      for (int r=0;r<NT;r++){
        const float4* qp = (const float4*)(qkv + (size_t)(n0+r)*3072 + (h<<6) + (c8<<3));
        float4 a = qp[0], b = qp[1];
        qv[r][0]=a.x;qv[r][1]=a.y;qv[r][2]=a.z;qv[r][3]=a.w;
        qv[r][4]=b.x;qv[r][5]=b.y;qv[r][6]=b.z;qv[r][7]=b.w;
      }
      #pragma unroll
      for (int j=0;j<8;j++){
        int m = tid + (j<<8);
        const float* kp = qkv + (size_t)m*3072 + 1024 + (h<<6) + (c8<<3);
        float4 k0 = *(const float4*)kp, k1 = *(const float4*)(kp+4);
        #pragma unroll
        for (int r=0;r<NT;r++){
          lg[r][j] += qv[r][0]*k0.x+qv[r][1]*k0.y+qv[r][2]*k0.z+qv[r][3]*k0.w
                    + qv[r][4]*k1.x+qv[r][5]*k1.y+qv[r][6]*k1.z+qv[r][7]*k1.w;
        }
      }
    }
    float mx[NT];
    #pragma unroll
    for (int r=0;r<NT;r++){
      float m0 = lg[r][0];
      #pragma unroll
      for (int j=1;j<8;j++) m0 = fmaxf(m0, lg[r][j]);
      mx[r]=m0;
    }
    #pragma unroll
    for (int off=32; off>0; off>>=1){
      #pragma unroll
      for (int r=0;r<NT;r++) mx[r] = fmaxf(mx[r], __shfl_xor(mx[r], off));
    }
    if (lane==0){
      #pragma unroll
      for (int r=0;r<NT;r++) redbuf[0][r][wvid] = mx[r];
    }
    __syncthreads();
    float ps[NT];
    #pragma unroll
    for (int r=0;r<NT;r++){
      float bm = fmaxf(fmaxf(redbuf[0][r][0],redbuf[0][r][1]),
                       fmaxf(redbuf[0][r][2],redbuf[0][r][3]));
      float s = 0.f;
      #pragma unroll
      for (int j=0;j<8;j++){ float p = __expf(lg[r][j]-bm); lg[r][j]=p; s+=p; }
      ps[r]=s;
    }
    #pragma unroll
    for (int off=32; off>0; off>>=1){
      #pragma unroll
      for (int r=0;r<NT;r++) ps[r] += __shfl_xor(ps[r], off);
    }
    if (lane==0){
      #pragma unroll
      for (int r=0;r<NT;r++) redbuf[1][r][wvid] = ps[r];
    }
    __syncthreads();
    #pragma unroll
    for (int r=0;r<NT;r++){
      float s = redbuf[1][r][0]+redbuf[1][r][1]+redbuf[1][r][2]+redbuf[1][r][3];
      float inv = 1.0f / s;
      #pragma unroll
      for (int j=0;j<8;j++){
        float w = lg[r][j]*inv;
        wsumr[r][j] += w;
        wrow[r][tid + (j<<8)] = w;
      }
    }
    __syncthreads();
    {
      const int c = wvid, d = lane;
      float part[NT];
      #pragma unroll
      for (int r=0;r<NT;r++) part[r]=0.f;
      const size_t vofs = 2048 + (h<<6) + d;
      for (int mm = c<<9; mm < ((c+1)<<9); mm += 4){
        float wf[NT][4];
        #pragma unroll
        for (int r=0;r<NT;r++)
          *(float4*)wf[r] = *(const float4*)&wrow[r][mm];
        #pragma unroll
        for (int e=0;e<4;e++){
          float vvv = qkv[(size_t)(mm+e)*3072 + vofs];
          #pragma unroll
          for (int r=0;r<NT;r++) part[r] += wf[r][e]*vvv;
        }
      }
      #pragma unroll
      for (int r=0;r<NT;r++) attp[c][r][d] = part[r];
    }
    __syncthreads();
    {
      const int r = wvid, d = lane;
      float s = attp[0][r][d]+attp[1][r][d]+attp[2][r][d]+attp[3][r][d];
      att[(size_t)(n0+r)*DMODEL + (h<<6) + d] = s;
    }
  }
  #pragma unroll
  for (int r=0;r<NT;r++){
    #pragma unroll
    for (int j=0;j<8;j++)
      meanw[(size_t)(n0+r)*NTOK + tid + (j<<8)] = wsumr[r][j]*0.0625f;
  }
}

// =====================================================================================
extern "C" void kernel_launch(void* const* d_in, const int* in_sizes, int n_in,
                              void* d_out, int out_size, void* d_ws, size_t ws_size,
                              hipStream_t stream)
{
  const float* x     = (const float*)d_in[0];
  const float* Wqkv  = (const float*)d_in[3];
  const float* bqkv  = (const float*)d_in[4];
  const float* Wpq   = (const float*)d_in[5];
  const float* bpq   = (const float*)d_in[6];
  const float* Wpk   = (const float*)d_in[7];
  const float* bpk   = (const float*)d_in[8];
  const float* Wo    = (const float*)d_in[9];
  const float* bo    = (const float*)d_in[10];
  const float* gamma = (const float*)d_in[11];
  const float* beta  = (const float*)d_in[12];

  float* out0 = (float*)d_out;                   // ln      [2048,1024] f32
  float* out1 = out0 + (size_t)NTOK*DMODEL;      // mean_w  [2048,2048] f32

  const size_t sz_qkvb = (size_t)NTOK*3072*2;          // 12.6 MB
  const size_t sz_vt   = (size_t)NH*HD*NTOK*2;         //  4.2 MB
  const size_t sz_pq   = (size_t)NTOK*64*4;            //  0.5 MB
  const size_t sz_attb = (size_t)NTOK*DMODEL*2;        //  4.2 MB
  const size_t sz_wot  = (size_t)DMODEL*DMODEL*2;      //  2.1 MB
  const size_t sz_pbuf = (size_t)NH*NTOK*NTOK*2;       // 134.2 MB
  const size_t sz_invS = (size_t)NH*NTOK*4;            //  0.13 MB
  const size_t need_fast = sz_qkvb + sz_vt + 2*sz_pq + sz_attb + sz_wot + sz_pbuf + sz_invS;

  char* ws = (char*)d_ws;
  if (ws_size >= need_fast){
    u16*   qkvb = (u16*)ws;    ws += sz_qkvb;
    u16*   vt   = (u16*)ws;    ws += sz_vt;
    float* pqb  = (float*)ws;  ws += sz_pq;
    float* pkb  = (float*)ws;  ws += sz_pq;
    u16*   attb = (u16*)ws;    ws += sz_attb;
    u16*   Wot  = (u16*)ws;    ws += sz_wot;
    u16*   pbuf = (u16*)ws;    ws += sz_pbuf;
    float* invS = (float*)ws;  ws += sz_invS;
    // xb and Wt alias the (dead-until-attention) pbuf region
    u16*   xb   = pbuf;                                        // 4.2 MB
    u16*   Wt   = pbuf + (size_t)NTOK*DMODEL;                  // 6.3 MB

    k_points  <<<NTOK,          128, 0, stream>>>(x, Wpq, bpq, Wpk, bpk, pqb, pkb, xb);
    k_tcvt    <<<dim3(48,16),   256, 0, stream>>>(Wqkv, Wt, DMODEL, 3*DMODEL);
    k_tcvt    <<<dim3(16,16),   256, 0, stream>>>(Wo, Wot, DMODEL, DMODEL);
    k_gemm    <<<768,           256, 0, stream>>>(xb, Wt, bqkv, nullptr, qkvb, nullptr,
                                                  NTOK, 3*DMODEL, DMODEL, 1);
    k_vt      <<<dim3(32,16),   256, 0, stream>>>(qkvb, vt);
    k_attn_qk <<<dim3(64,16),   512, 0, stream>>>(qkvb, pqb, pkb, pbuf, invS);
    k_pv      <<<512,           256, 0, stream>>>(pbuf, vt, invS, attb);
    k_meanw   <<<NTOK,          256, 0, stream>>>(pbuf, invS, out1);
    k_gemm    <<<256,           256, 0, stream>>>(attb, Wot, bo, x, nullptr, out0,
                                                  NTOK, DMODEL, DMODEL, 0);
    k_ln      <<<NTOK,          256, 0, stream>>>(out0, gamma, beta, out0);
  } else {
    float* qkv = (float*)ws; ws += (size_t)NTOK*3072*4;
    float* pqb = (float*)ws; ws += sz_pq;
    float* pkb = (float*)ws; ws += sz_pq;
    float* att = (float*)ws; ws += (size_t)NTOK*DMODEL*4;

    k_qkv_f32 <<<dim3(256,3), 256, 0, stream>>>(x, Wqkv, bqkv, qkv);
    k_points  <<<NTOK,        128, 0, stream>>>(x, Wpq, bpq, Wpk, bpk, pqb, pkb, nullptr);
    k_attn_f32<<<NTOK/NT,     256, 0, stream>>>(qkv, pqb, pkb, att, out1);
    k_out_f32 <<<256,         512, 0, stream>>>(att, Wo, bo, x, out0);
    k_ln      <<<NTOK,        256, 0, stream>>>(out0, gamma, beta, out0);
  }
}